// Round 4
// baseline (258859.375 us; speedup 1.0000x reference)
//
#include <hip/hip_runtime.h>
#include <stdint.h>

#define NT 600

// ---- ws layout (bytes) ----
// XT  [600][3][64] f32      @ 0        (460800)
// H1  [2][400][64] f32      @ 460800   (204800)
// H2  [2][400][64] f32      @ 665600   (204800)
// H3  [2][400][64] f32      @ 870400   (204800)
// C1  [400][64] f32         @ 1075200  (102400)
// C2  [400][64] f32         @ 1177600  (102400)
// C3  [400][64] f32         @ 1280000  (102400)
// WIN [2][77][64] f32       @ 1382400  (39424)
// KAP [64][10] f32          @ 1421824  (2560)
// BC  [3][1600] f32         @ 1424384  (19200)
// GY  [64][128] f32         @ 1443584  (32768)
// CNT [128] i32             @ 1476352  (512)     -> total 1476864 B
#define OFF_XT  0
#define OFF_H1  460800
#define OFF_H2  665600
#define OFF_H3  870400
#define OFF_C1  1075200
#define OFF_C2  1177600
#define OFF_C3  1280000
#define OFF_WIN 1382400
#define OFF_KAP 1421824
#define OFF_BC  1424384
#define OFF_GY  1443584
#define OFF_CNT 1476352

struct Params {
  const float* x; const int* cs; const int* cl; const float* bias;
  const float *Wih1,*Whh1,*bih1,*bhh1,*Wih2,*Whh2,*bih2,*bhh2,*Wih3,*Whh3,*bih3,*bhh3;
  const float *Watt,*batt,*Wgmm,*bgmm;
  float *XT,*H1,*H2,*H3,*C1,*C2,*C3,*WIN,*KAP,*BC,*GY;
  int *CNT;
  float* out;
};

__device__ __forceinline__ float sigm(float x) { return 1.f / (1.f + expf(-x)); }

// dot over a concat segment: weights wr[0..n), source src[k][b] (stride-64 batch-major)
__device__ __forceinline__ float dotseg(const float* __restrict__ wr,
                                        const float* __restrict__ src,
                                        int n, int b) {
  float a0 = 0.f, a1 = 0.f, a2 = 0.f, a3 = 0.f;
  int k = 0;
  for (; k + 4 <= n; k += 4) {
    a0 += wr[k + 0] * src[(k + 0)*64 + b];
    a1 += wr[k + 1] * src[(k + 1)*64 + b];
    a2 += wr[k + 2] * src[(k + 2)*64 + b];
    a3 += wr[k + 3] * src[(k + 3)*64 + b];
  }
  for (; k < n; ++k) a0 += wr[k] * src[k*64 + b];
  return (a0 + a1) + (a2 + a3);
}

// team barrier: monotone counter, release-add / relaxed-spin + acquire
__device__ __forceinline__ void tbar(int* c, int& ph) {
  __syncthreads();
  if (threadIdx.x == 0)
    __hip_atomic_fetch_add(c, 1, __ATOMIC_RELEASE, __HIP_MEMORY_SCOPE_AGENT);
  ph += 112;
  if (threadIdx.x == 0) {
    while (__hip_atomic_load(c, __ATOMIC_RELAXED, __HIP_MEMORY_SCOPE_AGENT) < ph)
      __builtin_amdgcn_s_sleep(1);
    (void)__hip_atomic_load(c, __ATOMIC_ACQUIRE, __HIP_MEMORY_SCOPE_AGENT);
  }
  __syncthreads();
}

// =====================  prep: zero state, transpose x, combine biases  =====================
__global__ void prep_k(Params P) {
  const long long NXT = 600LL*3*64;
  const long long NH  = 2LL*400*64;
  const long long NC  = 400LL*64;
  const long long NW  = 2LL*77*64;
  const long long NK  = 640;
  const long long NBc = 4800;
  const long long NCt = 128;
  const long long TOT = NXT + 3*NH + 3*NC + NW + NK + NBc + NCt;
  const long long stride = (long long)gridDim.x * blockDim.x;
  for (long long idx = (long long)blockIdx.x*blockDim.x + threadIdx.x; idx < TOT; idx += stride) {
    long long i = idx;
    if (i < NXT) {
      int t = (int)(i / 192);
      int rem = (int)(i % 192);
      int k = rem / 64, b = rem % 64;
      P.XT[i] = P.x[((size_t)b*NT + t)*3 + k];
      continue;
    }
    i -= NXT;
    if (i < NH)  { P.H1[i] = 0.f; continue; }  i -= NH;
    if (i < NH)  { P.H2[i] = 0.f; continue; }  i -= NH;
    if (i < NH)  { P.H3[i] = 0.f; continue; }  i -= NH;
    if (i < NC)  { P.C1[i] = 0.f; continue; }  i -= NC;
    if (i < NC)  { P.C2[i] = 0.f; continue; }  i -= NC;
    if (i < NC)  { P.C3[i] = 0.f; continue; }  i -= NC;
    if (i < NW)  { P.WIN[i] = 0.f; continue; } i -= NW;
    if (i < NK)  { P.KAP[i] = 0.f; continue; } i -= NK;
    if (i < NBc) {
      int l = (int)(i / 1600), r = (int)(i % 1600);
      const float* bi = (l==0)?P.bih1:(l==1)?P.bih2:P.bih3;
      const float* bh = (l==0)?P.bhh1:(l==1)?P.bhh2:P.bhh3;
      P.BC[i] = bi[r] + bh[r];
      continue;
    }
    i -= NBc;
    P.CNT[i] = 0;
  }
}

// =====================  phases (arithmetic identical to verified round-3 kernels) =====================

// L1: WG w (w<100) owns dims 4w..4w+3; 512 units = (dim,gate,batch32), 2 per thread.
__device__ void l1_phase(const Params& P, float* sm, int team, int w, int t) {
  const int tid = threadIdx.x;
  const int cu = t & 1, pv = (t + 1) & 1;
  float* gl = sm;  // [4][4][32]
#pragma unroll
  for (int ui = 0; ui < 2; ++ui) {
    int u = ui*256 + tid;
    int dd = u >> 7, g = (u >> 5) & 3, b32 = u & 31;
    int d = w*4 + dd, r = g*400 + d, b = team*32 + b32;
    const float* wih = P.Wih1 + (size_t)r*80;
    const float* whh = P.Whh1 + (size_t)r*400;
    float acc = P.BC[r];
    acc += dotseg(wih,      P.WIN + pv*77*64, 77, b);
    acc += dotseg(wih + 77, P.XT + t*192,      3, b);
    acc += dotseg(whh,      P.H1 + pv*25600, 400, b);
    gl[(dd*4 + g)*32 + b32] = acc;
  }
  __syncthreads();
  if (tid < 128) {
    int dd = tid >> 5, b32 = tid & 31;
    int d = w*4 + dd, b = team*32 + b32;
    float gi = gl[(dd*4+0)*32+b32], gf = gl[(dd*4+1)*32+b32];
    float gg = gl[(dd*4+2)*32+b32], go = gl[(dd*4+3)*32+b32];
    float c = sigm(gf)*P.C1[d*64+b] + sigm(gi)*tanhf(gg);
    P.C1[d*64+b] = c;
    P.H1[cu*25600 + d*64 + b] = sigm(go)*tanhf(c);
  }
}

template<int L>  // L=1 (LSTM2) or L=2 (LSTM3)
__device__ void l23_phase(const Params& P, float* sm, int team, int w, int t) {
  const int tid = threadIdx.x;
  const int cu = t & 1, pv = (t + 1) & 1;
  float* gl = sm;
  const float* Wih = (L==1) ? P.Wih2 : P.Wih3;
  const float* Whh = (L==1) ? P.Whh2 : P.Whh3;
  const int KIH = (L==1) ? 480 : 880;
  float* hOwn = (L==1) ? P.H2 : P.H3;
  float* cOwn = (L==1) ? P.C2 : P.C3;
#pragma unroll
  for (int ui = 0; ui < 2; ++ui) {
    int u = ui*256 + tid;
    int dd = u >> 7, g = (u >> 5) & 3, b32 = u & 31;
    int d = w*4 + dd, r = g*400 + d, b = team*32 + b32;
    const float* wih = Wih + (size_t)r*KIH;
    const float* whh = Whh + (size_t)r*400;
    float acc = P.BC[L*1600 + r];
    if (L == 1) {
      acc += dotseg(wih,       P.XT + t*192,      3, b);
      acc += dotseg(wih + 3,   P.H1 + cu*25600, 400, b);
      acc += dotseg(wih + 403, P.WIN + cu*77*64, 77, b);
    } else {
      acc += dotseg(wih,       P.XT + t*192,      3, b);
      acc += dotseg(wih + 3,   P.H1 + cu*25600, 400, b);
      acc += dotseg(wih + 403, P.H2 + cu*25600, 400, b);
      acc += dotseg(wih + 803, P.WIN + cu*77*64, 77, b);
    }
    acc += dotseg(whh, hOwn + pv*25600, 400, b);
    gl[(dd*4 + g)*32 + b32] = acc;
  }
  __syncthreads();
  if (tid < 128) {
    int dd = tid >> 5, b32 = tid & 31;
    int d = w*4 + dd, b = team*32 + b32;
    float gi = gl[(dd*4+0)*32+b32], gf = gl[(dd*4+1)*32+b32];
    float gg = gl[(dd*4+2)*32+b32], go = gl[(dd*4+3)*32+b32];
    float c = sigm(gf)*cOwn[d*64+b] + sigm(gi)*tanhf(gg);
    cOwn[d*64+b] = c;
    hOwn[cu*25600 + d*64 + b] = sigm(go)*tanhf(c);
  }
}

// GMM raw for step tt: WGs 100..111 (wgl 0..11), 3872 dots K=1200 -> GY[b][r]
__device__ void gmm_phase(const Params& P, int team, int wgl, int tt) {
  const int cu = tt & 1;
  for (int u = wgl*256 + threadIdx.x; u < 3872; u += 3072) {
    int r = u >> 5, b32 = u & 31, b = team*32 + b32;
    const float* wr = P.Wgmm + (size_t)r*1200;
    float acc = P.bgmm[r];
    acc += dotseg(wr,       P.H1 + cu*25600, 400, b);
    acc += dotseg(wr + 400, P.H2 + cu*25600, 400, b);
    acc += dotseg(wr + 800, P.H3 + cu*25600, 400, b);
    P.GY[b*128 + r] = acc;
  }
}

// attention window for batch b at step t (identical math to round-3 att_k)
__device__ void att_phase(const Params& P, float* sm, int b, int t) {
  const int tid = threadIdx.x, cu = t & 1;
  float* h1l  = sm;         // [400]
  float* abk  = sm + 400;   // [30]
  float* kapl = sm + 432;   // [10]
  float* phi  = sm + 448;   // [50]
  float* winl = sm + 512;   // [77]
  for (int d = tid; d < 400; d += 256) h1l[d] = P.H1[cu*25600 + d*64 + b];
  for (int a = tid; a < 77; a += 256) winl[a] = 0.f;
  __syncthreads();
  if (tid < 30) {
    const float* wr = P.Watt + tid*400;
    float a0=0.f,a1=0.f,a2=0.f,a3=0.f;
    for (int d = 0; d < 400; d += 4) {
      a0 += wr[d+0]*h1l[d+0]; a1 += wr[d+1]*h1l[d+1];
      a2 += wr[d+2]*h1l[d+2]; a3 += wr[d+3]*h1l[d+3];
    }
    abk[tid] = expf((a0+a1)+(a2+a3) + P.batt[tid]);
  }
  __syncthreads();
  if (tid < 10) {
    float kp = P.KAP[b*10 + tid] + abk[20 + tid];
    P.KAP[b*10 + tid] = kp;
    kapl[tid] = kp;
  }
  __syncthreads();
  if (tid < 50) {
    float s = 0.f;
    if (tid < P.cl[b]) {
      for (int k = 0; k < 10; ++k) {
        float dk = kapl[k] - (float)tid;
        s += abk[k]*expf(-abk[10 + k]*dk*dk);
      }
    }
    phi[tid] = s;
  }
  __syncthreads();
  if (tid == 0) {
    for (int u = 0; u < 50; ++u) winl[P.cs[b*50 + u]] += phi[u];
  }
  __syncthreads();
  for (int a = tid; a < 77; a += 256) P.WIN[cu*77*64 + a*64 + b] = winl[a];
}

// y epilogue for batch b, step tt (identical math to round-3 gmm_k epilogue)
__device__ void yepi_phase(const Params& P, float* sm, int b, int tt) {
  const int tid = threadIdx.x;
  float* raw = sm;        // [121]
  float* smx = sm + 128;  // [2]
  if (tid < 121) raw[tid] = P.GY[b*128 + tid];
  __syncthreads();
  const float bia = P.bias[b];
  if (tid == 0) {
    float m = -1e30f;
    for (int j = 1; j <= 20; ++j) m = fmaxf(m, raw[j]*(1.f + bia));
    float ss = 0.f;
    for (int j = 1; j <= 20; ++j) ss += expf(raw[j]*(1.f + bia) - m);
    smx[0] = m; smx[1] = ss;
  }
  __syncthreads();
  float* yr = P.out + ((size_t)b*NT + tt)*121;
  if (tid == 0)           yr[120] = 1.f/(1.f + expf(-raw[0]));
  else if (tid <= 20)     yr[tid - 1] = expf(raw[tid]*(1.f + bia) - smx[0]) / smx[1];
  else if (tid <= 60)     yr[80 + tid - 21] = raw[tid];
  else if (tid <= 100)    yr[20 + tid - 61] = expf(raw[tid] - bia);
  else if (tid <= 120)    yr[60 + tid - 101] = tanhf(raw[tid]);
}

// =====================  persistent kernel: 2 teams x 112 WGs  =====================
__global__ __launch_bounds__(256) void rnn_pers(Params P) {
  __shared__ __align__(16) float sm[592];
  const int team = blockIdx.x / 112;
  const int w = blockIdx.x % 112;
  int* C = P.CNT + team*64;
  int ph = 0;
  for (int t = 0; t <= NT; ++t) {
    // Phase 1: L1(t) on WGs 0..99  ||  GMM(t-1) on WGs 100..111
    if (w < 100) { if (t < NT) l1_phase(P, sm, team, w, t); }
    else if (t >= 1) gmm_phase(P, team, w - 100, t - 1);
    tbar(C, ph);
    // Phase 2: att(t) on WGs 0..31  ||  y-epilogue(t-1) on WGs 32..63
    if (w < 32) { if (t < NT) att_phase(P, sm, team*32 + w, t); }
    else if (w < 64) { if (t >= 1) yepi_phase(P, sm, team*32 + (w - 32), t - 1); }
    tbar(C, ph);
    if (t == NT) break;
    // Phase 3: L2(t)
    if (w < 100) l23_phase<1>(P, sm, team, w, t);
    tbar(C, ph);
    // Phase 4: L3(t)
    if (w < 100) l23_phase<2>(P, sm, team, w, t);
    tbar(C, ph);
  }
}

extern "C" void kernel_launch(void* const* d_in, const int* in_sizes, int n_in,
                              void* d_out, int out_size, void* d_ws, size_t ws_size,
                              hipStream_t stream) {
  (void)in_sizes; (void)n_in; (void)out_size; (void)ws_size;
  Params P;
  P.x    = (const float*)d_in[0];
  P.cs   = (const int*)d_in[1];
  P.cl   = (const int*)d_in[2];
  P.bias = (const float*)d_in[3];
  P.Wih1 = (const float*)d_in[4];  P.Whh1 = (const float*)d_in[5];
  P.bih1 = (const float*)d_in[6];  P.bhh1 = (const float*)d_in[7];
  P.Wih2 = (const float*)d_in[8];  P.Whh2 = (const float*)d_in[9];
  P.bih2 = (const float*)d_in[10]; P.bhh2 = (const float*)d_in[11];
  P.Wih3 = (const float*)d_in[12]; P.Whh3 = (const float*)d_in[13];
  P.bih3 = (const float*)d_in[14]; P.bhh3 = (const float*)d_in[15];
  P.Watt = (const float*)d_in[16]; P.batt = (const float*)d_in[17];
  P.Wgmm = (const float*)d_in[18]; P.bgmm = (const float*)d_in[19];
  char* ws = (char*)d_ws;
  P.XT  = (float*)(ws + OFF_XT);
  P.H1  = (float*)(ws + OFF_H1);
  P.H2  = (float*)(ws + OFF_H2);
  P.H3  = (float*)(ws + OFF_H3);
  P.C1  = (float*)(ws + OFF_C1);
  P.C2  = (float*)(ws + OFF_C2);
  P.C3  = (float*)(ws + OFF_C3);
  P.WIN = (float*)(ws + OFF_WIN);
  P.KAP = (float*)(ws + OFF_KAP);
  P.BC  = (float*)(ws + OFF_BC);
  P.GY  = (float*)(ws + OFF_GY);
  P.CNT = (int*)(ws + OFF_CNT);
  P.out = (float*)d_out;

  hipLaunchKernelGGL(prep_k, dim3(512), dim3(256), 0, stream, P);
  hipLaunchKernelGGL(rnn_pers, dim3(224), dim3(256), 0, stream, P);
}

// Round 5
// 52163.141 us; speedup vs baseline: 4.9625x; 4.9625x over previous
//
#include <hip/hip_runtime.h>
#include <stdint.h>

#define NT 600

// ---- ws layout (bytes) ----
#define OFF_XT  0          // [600][3][64] f32   460800
#define OFF_H1  460800     // [2][400][64] f32   204800
#define OFF_H2  665600
#define OFF_H3  870400
#define OFF_WIN 1075200    // [2][77][64] f32    39424
#define OFF_KAP 1114624    // [64][10] f32       2560
#define OFF_BC  1117184    // [3][1600] f32      19200
#define OFF_GY  1136384    // [64][128] f32      32768
#define OFF_CNT 1169152    // [8*16] i32         512

typedef float f32x4 __attribute__((ext_vector_type(4)));

struct Params {
  const float* x; const int* cs; const int* cl; const float* bias;
  const float *Wih1,*Whh1,*bih1,*bhh1,*Wih2,*Whh2,*bih2,*bhh2,*Wih3,*Whh3,*bih3,*bhh3;
  const float *Watt,*batt,*Wgmm,*bgmm;
  float *XT,*H1,*H2,*H3,*WIN,*KAP,*BC,*GY;
  int *CNT;
  float* out;
};

__device__ __forceinline__ float sigm(float x) { return 1.f / (1.f + expf(-x)); }

// 8-sub-counter team barrier over 224 WGs (28 per sub-counter)
__device__ __forceinline__ void tbar(int* C, int wmod, int& ph) {
  __syncthreads();
  if (threadIdx.x == 0)
    __hip_atomic_fetch_add(&C[wmod*16], 1, __ATOMIC_RELEASE, __HIP_MEMORY_SCOPE_AGENT);
  ++ph;
  const int tgt = 28*ph;
  if (threadIdx.x < 8) {
    while (__hip_atomic_load(&C[threadIdx.x*16], __ATOMIC_RELAXED, __HIP_MEMORY_SCOPE_AGENT) < tgt)
      __builtin_amdgcn_s_sleep(1);
    (void)__hip_atomic_load(&C[threadIdx.x*16], __ATOMIC_ACQUIRE, __HIP_MEMORY_SCOPE_AGENT);
  }
  __syncthreads();
}

// =====================  prep  =====================
__global__ void prep_k(Params P) {
  const long long NXT = 600LL*3*64;
  const long long NH  = 2LL*400*64;
  const long long NW  = 2LL*77*64;
  const long long NK  = 640;
  const long long NBc = 4800;
  const long long NCt = 128;
  const long long TOT = NXT + 3*NH + NW + NK + NBc + NCt;
  const long long stride = (long long)gridDim.x * blockDim.x;
  for (long long idx = (long long)blockIdx.x*blockDim.x + threadIdx.x; idx < TOT; idx += stride) {
    long long i = idx;
    if (i < NXT) {
      int t = (int)(i / 192);
      int rem = (int)(i % 192);
      int k = rem / 64, b = rem % 64;
      P.XT[i] = P.x[((size_t)b*NT + t)*3 + k];
      continue;
    }
    i -= NXT;
    if (i < NH)  { P.H1[i] = 0.f; continue; }  i -= NH;
    if (i < NH)  { P.H2[i] = 0.f; continue; }  i -= NH;
    if (i < NH)  { P.H3[i] = 0.f; continue; }  i -= NH;
    if (i < NW)  { P.WIN[i] = 0.f; continue; } i -= NW;
    if (i < NK)  { P.KAP[i] = 0.f; continue; } i -= NK;
    if (i < NBc) {
      int l = (int)(i / 1600), r = (int)(i % 1600);
      const float* bi = (l==0)?P.bih1:(l==1)?P.bih2:P.bih3;
      const float* bh = (l==0)?P.bhh1:(l==1)?P.bhh2:P.bhh3;
      P.BC[i] = bi[r] + bh[r];
      continue;
    }
    i -= NBc;
    P.CNT[i] = 0;
  }
}

// =====================  phases  =====================

// LSTM phase: WG w<200 owns dims {2w,2w+1} (8 gate rows). Lanes=batch, waves=K-slices.
template<int L>
__device__ __forceinline__ void lphase(const Params& P, const float* WtF, float* scrF,
                                       const float* bcl, int w, int t, float& cref) {
  const int tid = threadIdx.x, ks = tid >> 6, b = tid & 63;
  const int cu = t & 1, pv = (t + 1) & 1;
  const float* sp[5]; int sl[5]; int ns;
  if (L == 0) {
    sp[0] = P.WIN + pv*4928; sl[0] = 77;
    sp[1] = P.XT + t*192;    sl[1] = 3;
    sp[2] = P.H1 + pv*25600; sl[2] = 400;
    ns = 3;
  } else if (L == 1) {
    sp[0] = P.XT + t*192;    sl[0] = 3;
    sp[1] = P.H1 + cu*25600; sl[1] = 400;
    sp[2] = P.WIN + cu*4928; sl[2] = 77;
    sp[3] = P.H2 + pv*25600; sl[3] = 400;
    ns = 4;
  } else {
    sp[0] = P.XT + t*192;    sl[0] = 3;
    sp[1] = P.H1 + cu*25600; sl[1] = 400;
    sp[2] = P.H2 + cu*25600; sl[2] = 400;
    sp[3] = P.WIN + cu*4928; sl[3] = 77;
    sp[4] = P.H3 + pv*25600; sl[4] = 400;
    ns = 5;
  }
  const int base = (L==0) ? 0 : (L==1) ? 3840 : 10880;
  f32x4 a0 = {0.f,0.f,0.f,0.f}, a1 = {0.f,0.f,0.f,0.f};
  int segw = 0;
  for (int s = 0; s < ns; ++s) {
    const int len = sl[s];
    const int lo = (len*ks) >> 2, hi = (len*(ks+1)) >> 2;
    const float* p = sp[s];
    const float* wb = WtF + base + (size_t)segw*8;
#pragma unroll 4
    for (int i = lo; i < hi; ++i) {
      float sv = p[i*64 + b];
      const f32x4* wk = (const f32x4*)(wb + (size_t)i*8);
      a0 += wk[0]*sv; a1 += wk[1]*sv;
    }
    segw += len;
  }
  *(f32x4*)&scrF[(ks*64 + b)*8]     = a0;
  *(f32x4*)&scrF[(ks*64 + b)*8 + 4] = a1;
  __syncthreads();
  if (tid < 128) {
    const int dd = tid >> 6, bb = tid & 63, d = 2*w + dd;
    float g4[4];
#pragma unroll
    for (int g = 0; g < 4; ++g) {
      int r = dd*4 + g;
      float D = scrF[(0*64+bb)*8 + r] + scrF[(1*64+bb)*8 + r]
              + scrF[(2*64+bb)*8 + r] + scrF[(3*64+bb)*8 + r];
      g4[g] = D + bcl[L*8 + r];
    }
    float c = sigm(g4[1])*cref + sigm(g4[0])*tanhf(g4[2]);
    cref = c;
    float h = sigm(g4[3])*tanhf(c);
    float* H = (L==0) ? P.H1 : (L==1) ? P.H2 : P.H3;
    H[cu*25600 + d*64 + bb] = h;
  }
}

// GMM raw rows rlo..rlo+nr for step tt -> GY[b][r]
__device__ __forceinline__ void gmm_do(const Params& P, const float* WgF, float* scrF,
                                       const float* bgl, int rlo, int nr, int tt) {
  const int tid = threadIdx.x, ks = tid >> 6, b = tid & 63, cu = tt & 1;
  const float* sp[3] = {P.H1 + cu*25600, P.H2 + cu*25600, P.H3 + cu*25600};
  f32x4 a0 = {0.f,0.f,0.f,0.f}, a1 = {0.f,0.f,0.f,0.f};
  for (int s = 0; s < 3; ++s) {
    const float* p = sp[s];
    const float* wb = WgF + (size_t)s*400*8;
    const int lo = ks*100, hi = lo + 100;
#pragma unroll 4
    for (int i = lo; i < hi; ++i) {
      float sv = p[i*64 + b];
      const f32x4* wk = (const f32x4*)(wb + (size_t)i*8);
      a0 += wk[0]*sv; a1 += wk[1]*sv;
    }
  }
  *(f32x4*)&scrF[(ks*64 + b)*8]     = a0;
  *(f32x4*)&scrF[(ks*64 + b)*8 + 4] = a1;
  __syncthreads();
  if (tid < 64) {
    for (int j = 0; j < nr; ++j) {
      float D = scrF[(0*64+tid)*8+j] + scrF[(1*64+tid)*8+j]
              + scrF[(2*64+tid)*8+j] + scrF[(3*64+tid)*8+j] + bgl[j];
      P.GY[tid*128 + rlo + j] = D;
    }
  }
}

// attention window (batch b), math identical to verified round-3 kernel
__device__ __forceinline__ void att_do(const Params& P, const float* WaF, float* h1l,
    float* parts, float* abk, float* kapl, float* phi, float* winl,
    const float* batl, const int* csl, const int* cll, int b, int t) {
  const int tid = threadIdx.x, cu = t & 1;
  for (int d = tid; d < 400; d += 256) h1l[d] = P.H1[cu*25600 + d*64 + b];
  if (tid < 77) winl[tid] = 0.f;
  __syncthreads();
  if (tid < 240) {
    int j = tid >> 3, pp = tid & 7;
    const float* wr = WaF + j*400 + pp*50;
    const float* hr = h1l + pp*50;
    float acc = 0.f;
#pragma unroll 5
    for (int d2 = 0; d2 < 50; ++d2) acc += wr[d2]*hr[d2];
    parts[tid] = acc;
  }
  __syncthreads();
  if (tid < 30) {
    float s = batl[tid];
#pragma unroll
    for (int pp = 0; pp < 8; ++pp) s += parts[tid*8 + pp];
    abk[tid] = expf(s);
  }
  __syncthreads();
  if (tid < 10) {
    float kp = P.KAP[b*10 + tid] + abk[20 + tid];
    P.KAP[b*10 + tid] = kp;
    kapl[tid] = kp;
  }
  __syncthreads();
  if (tid < 50) {
    float s = 0.f;
    if (tid < cll[0]) {
#pragma unroll
      for (int k = 0; k < 10; ++k) {
        float dk = kapl[k] - (float)tid;
        s += abk[k]*expf(-abk[10 + k]*dk*dk);
      }
    }
    phi[tid] = s;
  }
  __syncthreads();
  if (tid == 0) {
    for (int u = 0; u < 50; ++u) winl[csl[u]] += phi[u];
  }
  __syncthreads();
  if (tid < 77) P.WIN[cu*4928 + tid*64 + b] = winl[tid];
}

// y epilogue (batch b, step tt), identical math to verified round-3 kernel
__device__ __forceinline__ void yepi_do(const Params& P, float* rawl, float* smx, int b, int tt) {
  const int tid = threadIdx.x;
  if (tid < 121) rawl[tid] = P.GY[b*128 + tid];
  __syncthreads();
  const float bia = P.bias[b];
  if (tid == 0) {
    float m = -1e30f;
    for (int j = 1; j <= 20; ++j) m = fmaxf(m, rawl[j]*(1.f + bia));
    float ss = 0.f;
    for (int j = 1; j <= 20; ++j) ss += expf(rawl[j]*(1.f + bia) - m);
    smx[0] = m; smx[1] = ss;
  }
  __syncthreads();
  float* yr = P.out + ((size_t)b*NT + tt)*121;
  if (tid == 0)           yr[120] = 1.f/(1.f + expf(-rawl[0]));
  else if (tid <= 20)     yr[tid - 1] = expf(rawl[tid]*(1.f + bia) - smx[0]) / smx[1];
  else if (tid <= 60)     yr[80 + tid - 21] = rawl[tid];
  else if (tid <= 100)    yr[20 + tid - 61] = expf(rawl[tid] - bia);
  else if (tid <= 120)    yr[60 + tid - 101] = tanhf(rawl[tid]);
}

// =====================  persistent kernel: 224 WGs, 1 team of 64 batches  =====================
__global__ __launch_bounds__(256, 1) void rnn_pers(Params P) {
  __shared__ __align__(16) char smem[145408];
  float* WtF  = (float*)smem;                 // main: Wt[21120] transposed [k][8]; gmm: Wgt[9600]
  float* WaF  = (float*)(smem + 84480);       // Watt [12000] (w<64)
  float* scrF = (float*)(smem + 132480);      // [4][64][8]
  float* M    = (float*)(smem + 140672);
  float* bcl  = M;            // 24
  float* bgl  = M + 24;       // 8
  float* h1l  = M + 32;       // 400 (also yepi rawl)
  float* parts= M + 432;      // 240
  float* abk  = M + 672;      // 30
  float* kapl = M + 702;      // 10
  float* phi  = M + 712;      // 50
  float* winl = M + 762;      // 77
  float* batl = M + 839;      // 30
  float* smx  = M + 869;      // 2
  int*   csl  = (int*)(M + 871); // 50
  int*   cll  = (int*)(M + 921); // 1

  const int w = blockIdx.x, tid = threadIdx.x;
  int rlo = 0, nr = 0;

  // ---- one-time staging into LDS ----
  if (w < 200) {
    const float* WihA[3] = {P.Wih1, P.Wih2, P.Wih3};
    const float* WhhA[3] = {P.Whh1, P.Whh2, P.Whh3};
    const int KL[3] = {480, 880, 1280}, KIH[3] = {80, 480, 880}, BASE[3] = {0, 3840, 10880};
    for (int L = 0; L < 3; ++L)
      for (int slot = 0; slot < 8; ++slot) {
        int dd = slot >> 2, g = slot & 3, gr = g*400 + 2*w + dd;
        const float* ih = WihA[L] + (size_t)gr*KIH[L];
        const float* hh = WhhA[L] + (size_t)gr*400;
        for (int k = tid; k < KL[L]; k += 256)
          WtF[BASE[L] + k*8 + slot] = (k < KIH[L]) ? ih[k] : hh[k - KIH[L]];
      }
    if (tid < 24) {
      int L = tid >> 3, slot = tid & 7, dd = slot >> 2, g = slot & 3;
      bcl[tid] = P.BC[L*1600 + g*400 + 2*w + dd];
    }
    if (w < 64) {
      for (int i = tid; i < 12000; i += 256) WaF[i] = P.Watt[i];
      if (tid < 30) batl[tid] = P.batt[tid];
      if (tid < 50) csl[tid] = P.cs[w*50 + tid];
      if (tid == 0) cll[0] = P.cl[w];
    }
  } else {
    int q = w - 200;
    rlo = (121*q)/24;
    nr  = (121*(q+1))/24 - rlo;
    for (int j = 0; j < 8; ++j)
      for (int k = tid; k < 1200; k += 256)
        WtF[k*8 + j] = (j < nr) ? P.Wgmm[(size_t)(rlo + j)*1200 + k] : 0.f;
    if (tid < 8) bgl[tid] = (tid < nr) ? P.bgmm[rlo + tid] : 0.f;
  }
  __syncthreads();

  int ph = 0;
  float c1 = 0.f, c2 = 0.f, c3 = 0.f;
  for (int t = 0; t <= NT; ++t) {
    // P1: L1(t) on mains || GMM(t-1) on GMM WGs
    if (w < 200) { if (t < NT) lphase<0>(P, WtF, scrF, bcl, w, t, c1); }
    else if (t >= 1) gmm_do(P, WtF, scrF, bgl, rlo, nr, t - 1);
    tbar(P.CNT, w & 7, ph);
    // P2: att(t) on w<64 || y-epilogue(t-1) on w in [64,128)
    if (w < 64) { if (t < NT) att_do(P, WaF, h1l, parts, abk, kapl, phi, winl, batl, csl, cll, w, t); }
    else if (w < 128) { if (t >= 1) yepi_do(P, h1l, smx, w - 64, t - 1); }
    tbar(P.CNT, w & 7, ph);
    if (t == NT) break;
    // P3: L2(t)
    if (w < 200) lphase<1>(P, WtF, scrF, bcl, w, t, c2);
    tbar(P.CNT, w & 7, ph);
    // P4: L3(t)
    if (w < 200) lphase<2>(P, WtF, scrF, bcl, w, t, c3);
    tbar(P.CNT, w & 7, ph);
  }
}

extern "C" void kernel_launch(void* const* d_in, const int* in_sizes, int n_in,
                              void* d_out, int out_size, void* d_ws, size_t ws_size,
                              hipStream_t stream) {
  (void)in_sizes; (void)n_in; (void)out_size; (void)ws_size;
  Params P;
  P.x    = (const float*)d_in[0];
  P.cs   = (const int*)d_in[1];
  P.cl   = (const int*)d_in[2];
  P.bias = (const float*)d_in[3];
  P.Wih1 = (const float*)d_in[4];  P.Whh1 = (const float*)d_in[5];
  P.bih1 = (const float*)d_in[6];  P.bhh1 = (const float*)d_in[7];
  P.Wih2 = (const float*)d_in[8];  P.Whh2 = (const float*)d_in[9];
  P.bih2 = (const float*)d_in[10]; P.bhh2 = (const float*)d_in[11];
  P.Wih3 = (const float*)d_in[12]; P.Whh3 = (const float*)d_in[13];
  P.bih3 = (const float*)d_in[14]; P.bhh3 = (const float*)d_in[15];
  P.Watt = (const float*)d_in[16]; P.batt = (const float*)d_in[17];
  P.Wgmm = (const float*)d_in[18]; P.bgmm = (const float*)d_in[19];
  char* ws = (char*)d_ws;
  P.XT  = (float*)(ws + OFF_XT);
  P.H1  = (float*)(ws + OFF_H1);
  P.H2  = (float*)(ws + OFF_H2);
  P.H3  = (float*)(ws + OFF_H3);
  P.WIN = (float*)(ws + OFF_WIN);
  P.KAP = (float*)(ws + OFF_KAP);
  P.BC  = (float*)(ws + OFF_BC);
  P.GY  = (float*)(ws + OFF_GY);
  P.CNT = (int*)(ws + OFF_CNT);
  P.out = (float*)d_out;

  hipLaunchKernelGGL(prep_k, dim3(512), dim3(256), 0, stream, P);
  hipLaunchKernelGGL(rnn_pers, dim3(224), dim3(256), 0, stream, P);
}

// Round 6
// 38694.681 us; speedup vs baseline: 6.6898x; 1.3481x over previous
//
#include <hip/hip_runtime.h>
#include <stdint.h>

#define NT 600

// ---- ws layout (bytes) ----
#define OFF_XTH  0          // [600][64][8]  f16   614400
#define OFF_H1F  614400     // [2][400][64]  f32   204800  (att reads)
#define OFF_H1H  819200     // [2][64][400]  f16   102400
#define OFF_H2H  921600     // [2][64][400]  f16   102400
#define OFF_H3H  1024000    // [2][64][400]  f16   102400
#define OFF_WINH 1126400    // [2][64][80]   f16   20480
#define OFF_KAP  1146880    // [64][10]      f32   2560
#define OFF_BC   1149440    // [3][1600]     f32   19200
#define OFF_GY   1168640    // [64][128]     f32   32768
#define OFF_CNT  1201408    // [8*16]        i32   512

// padded K layouts (every segment a multiple of 8)
// L1: win[0,80) x[80,88) h1[88,488)                   KP1=488
// L2: x[0,8) h1[8,408) win[408,488) h2[488,888)       KP2=888
// L3: x[0,8) h1[8,408) h2[408,808) win[808,888) h3[888,1288) KP3=1288
#define KP1 488
#define KP2 888
#define KP3 1288
#define BASE1 0
#define BASE2 3904     // 488*8
#define BASE3 11008    // (488+888)*8

typedef float f32x4 __attribute__((ext_vector_type(4)));
typedef _Float16 f16x8 __attribute__((ext_vector_type(8)));

struct Params {
  const float* x; const int* cs; const int* cl; const float* bias;
  const float *Wih1,*Whh1,*bih1,*bhh1,*Wih2,*Whh2,*bih2,*bhh2,*Wih3,*Whh3,*bih3,*bhh3;
  const float *Watt,*batt,*Wgmm,*bgmm;
  _Float16 *XTH,*H1H,*H2H,*H3H,*WINH;
  float *H1F,*KAP,*BC,*GY;
  int *CNT;
  float* out;
};

__device__ __forceinline__ float sigm(float x) { return 1.f / (1.f + expf(-x)); }

// 8-sub-counter barrier over 224 WGs (28 per sub-counter)
__device__ __forceinline__ void tbar(int* C, int wmod, int& ph) {
  __syncthreads();
  if (threadIdx.x == 0)
    __hip_atomic_fetch_add(&C[wmod*16], 1, __ATOMIC_RELEASE, __HIP_MEMORY_SCOPE_AGENT);
  ++ph;
  const int tgt = 28*ph;
  if (threadIdx.x < 8) {
    while (__hip_atomic_load(&C[threadIdx.x*16], __ATOMIC_RELAXED, __HIP_MEMORY_SCOPE_AGENT) < tgt)
      __builtin_amdgcn_s_sleep(1);
    (void)__hip_atomic_load(&C[threadIdx.x*16], __ATOMIC_ACQUIRE, __HIP_MEMORY_SCOPE_AGENT);
  }
  __syncthreads();
}

// =====================  prep  =====================
__global__ void prep_k(Params P) {
  const long long NX  = 600LL*512;      // XTH elems
  const long long NHF = 51200;          // H1F
  const long long NHH = 51200;          // per HxH
  const long long NWH = 10240;
  const long long NK  = 640;
  const long long NBc = 4800;
  const long long NCt = 128;
  const long long TOT = NX + NHF + 3*NHH + NWH + NK + NBc + NCt;
  const long long stride = (long long)gridDim.x * blockDim.x;
  for (long long idx = (long long)blockIdx.x*blockDim.x + threadIdx.x; idx < TOT; idx += stride) {
    long long i = idx;
    if (i < NX) {
      int t = (int)(i >> 9);
      int rem = (int)(i & 511);
      int b = rem >> 3, k = rem & 7;
      float v = (k < 3) ? P.x[((size_t)b*NT + t)*3 + k] : 0.f;
      P.XTH[i] = (_Float16)v;
      continue;
    }
    i -= NX;
    if (i < NHF) { P.H1F[i] = 0.f; continue; }          i -= NHF;
    if (i < NHH) { P.H1H[i] = (_Float16)0.f; continue; } i -= NHH;
    if (i < NHH) { P.H2H[i] = (_Float16)0.f; continue; } i -= NHH;
    if (i < NHH) { P.H3H[i] = (_Float16)0.f; continue; } i -= NHH;
    if (i < NWH) { P.WINH[i] = (_Float16)0.f; continue; } i -= NWH;
    if (i < NK)  { P.KAP[i] = 0.f; continue; }           i -= NK;
    if (i < NBc) {
      int l = (int)(i / 1600), r = (int)(i % 1600);
      const float* bi = (l==0)?P.bih1:(l==1)?P.bih2:P.bih3;
      const float* bh = (l==0)?P.bhh1:(l==1)?P.bhh2:P.bhh3;
      P.BC[i] = bi[r] + bh[r];
      continue;
    }
    i -= NBc;
    P.CNT[i] = 0;
  }
}

// =====================  LSTM phase =====================
// WG w<200 owns dims {2w,2w+1} = 8 gate rows (r = dd*4+g). 8 waves split k-chunks.
template<int L>
__device__ __forceinline__ void lphase(const Params& P, const float* WtF, float* scrF,
                                       const float* bcl, int w, int t, float& cref) {
  const int tid = threadIdx.x, ks = tid >> 6, b = tid & 63;
  const int cu = t & 1, pv = (t + 1) & 1;
  const _Float16* sp[5]; int nch[5], kb[5], rl[5]; int ns;
  if (L == 0) {
    sp[0] = P.WINH + pv*5120;  nch[0] = 10; kb[0] = 0;   rl[0] = 80;
    sp[1] = P.XTH + t*512;     nch[1] = 1;  kb[1] = 80;  rl[1] = 8;
    sp[2] = P.H1H + pv*25600;  nch[2] = 50; kb[2] = 88;  rl[2] = 400;
    ns = 3;
  } else if (L == 1) {
    sp[0] = P.XTH + t*512;     nch[0] = 1;  kb[0] = 0;   rl[0] = 8;
    sp[1] = P.H1H + cu*25600;  nch[1] = 50; kb[1] = 8;   rl[1] = 400;
    sp[2] = P.WINH + cu*5120;  nch[2] = 10; kb[2] = 408; rl[2] = 80;
    sp[3] = P.H2H + pv*25600;  nch[3] = 50; kb[3] = 488; rl[3] = 400;
    ns = 4;
  } else {
    sp[0] = P.XTH + t*512;     nch[0] = 1;  kb[0] = 0;   rl[0] = 8;
    sp[1] = P.H1H + cu*25600;  nch[1] = 50; kb[1] = 8;   rl[1] = 400;
    sp[2] = P.H2H + cu*25600;  nch[2] = 50; kb[2] = 408; rl[2] = 400;
    sp[3] = P.WINH + cu*5120;  nch[3] = 10; kb[3] = 808; rl[3] = 80;
    sp[4] = P.H3H + pv*25600;  nch[4] = 50; kb[4] = 888; rl[4] = 400;
    ns = 5;
  }
  const int base = (L==0) ? BASE1 : (L==1) ? BASE2 : BASE3;
  f32x4 a0 = {0.f,0.f,0.f,0.f}, a1 = {0.f,0.f,0.f,0.f};
  for (int s = 0; s < ns; ++s) {
    const _Float16* p = sp[s] + (size_t)b*rl[s];
    const float* wb = WtF + base + (size_t)kb[s]*8;
    for (int c = ks; c < nch[s]; c += 8) {
      f16x8 v = *(const f16x8*)(p + c*8);
      const f32x4* wk = (const f32x4*)(wb + (size_t)c*64);
#pragma unroll
      for (int k2 = 0; k2 < 8; ++k2) {
        float sv = (float)v[k2];
        a0 += wk[k2*2]*sv; a1 += wk[k2*2+1]*sv;
      }
    }
  }
  *(f32x4*)&scrF[(ks*64 + b)*8]     = a0;
  *(f32x4*)&scrF[(ks*64 + b)*8 + 4] = a1;
  __syncthreads();
  // reduce: thread (b2 = tid>>3, r = tid&7)
  const int r = tid & 7;
  float D = 0.f;
#pragma unroll
  for (int k = 0; k < 8; ++k) D += scrF[k*512 + tid];
  D += bcl[L*8 + r];
  float v1 = __shfl_xor(D, 1);
  float v2 = __shfl_xor(D, 2);
  float v3 = __shfl_xor(D, 3);
  if ((tid & 3) == 0) {   // r in {0,4}: dd = r>>2, gates (gi,gf,gg,go) = (D,v1,v2,v3)
    float c = sigm(v1)*cref + sigm(D)*tanhf(v2);
    cref = c;
    float h = sigm(v3)*tanhf(c);
    const int dd = r >> 2, b2 = tid >> 3, d = 2*w + dd;
    _Float16* HH = (L==0) ? P.H1H : (L==1) ? P.H2H : P.H3H;
    HH[cu*25600 + b2*400 + d] = (_Float16)h;
    if (L == 0) P.H1F[cu*25600 + d*64 + b2] = h;
  }
}

// GMM raw rows rlo..rlo+nr-1 for step tt -> GY[b][r]
__device__ __forceinline__ void gmm_do(const Params& P, const float* WgF, float* scrF,
                                       const float* bgl, int rlo, int nr, int tt) {
  const int tid = threadIdx.x, ks = tid >> 6, b = tid & 63, cu = tt & 1;
  const _Float16* sp[3] = {P.H1H + cu*25600, P.H2H + cu*25600, P.H3H + cu*25600};
  f32x4 a0 = {0.f,0.f,0.f,0.f}, a1 = {0.f,0.f,0.f,0.f};
  for (int s = 0; s < 3; ++s) {
    const _Float16* p = sp[s] + (size_t)b*400;
    const float* wb = WgF + (size_t)s*3200;
    for (int c = ks; c < 50; c += 8) {
      f16x8 v = *(const f16x8*)(p + c*8);
      const f32x4* wk = (const f32x4*)(wb + (size_t)c*64);
#pragma unroll
      for (int k2 = 0; k2 < 8; ++k2) {
        float sv = (float)v[k2];
        a0 += wk[k2*2]*sv; a1 += wk[k2*2+1]*sv;
      }
    }
  }
  *(f32x4*)&scrF[(ks*64 + b)*8]     = a0;
  *(f32x4*)&scrF[(ks*64 + b)*8 + 4] = a1;
  __syncthreads();
  const int r = tid & 7, b2 = tid >> 3;
  float D = 0.f;
#pragma unroll
  for (int k = 0; k < 8; ++k) D += scrF[k*512 + tid];
  if (r < nr) P.GY[b2*128 + rlo + r] = D + bgl[r];
}

// attention window (batch b): identical math to round-5 kernel
__device__ __forceinline__ void att_do(const Params& P, const float* WaF, float* h1l,
    float* parts, float* abk, float* kapl, float* phi, float* winl,
    const float* batl, const int* csl, const int* cll, int b, int t) {
  const int tid = threadIdx.x, cu = t & 1;
  for (int d = tid; d < 400; d += 512) h1l[d] = P.H1F[cu*25600 + d*64 + b];
  if (tid < 80) winl[tid] = 0.f;
  __syncthreads();
  if (tid < 240) {
    int j = tid >> 3, pp = tid & 7;
    const float* wr = WaF + j*400 + pp*50;
    const float* hr = h1l + pp*50;
    float acc = 0.f;
#pragma unroll 5
    for (int d2 = 0; d2 < 50; ++d2) acc += wr[d2]*hr[d2];
    parts[tid] = acc;
  }
  __syncthreads();
  if (tid < 30) {
    float s = batl[tid];
#pragma unroll
    for (int pp = 0; pp < 8; ++pp) s += parts[tid*8 + pp];
    abk[tid] = expf(s);
  }
  __syncthreads();
  if (tid < 10) {
    float kp = P.KAP[b*10 + tid] + abk[20 + tid];
    P.KAP[b*10 + tid] = kp;
    kapl[tid] = kp;
  }
  __syncthreads();
  if (tid < 50) {
    float s = 0.f;
    if (tid < cll[0]) {
#pragma unroll
      for (int k = 0; k < 10; ++k) {
        float dk = kapl[k] - (float)tid;
        s += abk[k]*expf(-abk[10 + k]*dk*dk);
      }
    }
    phi[tid] = s;
  }
  __syncthreads();
  if (tid == 0) {
    for (int u = 0; u < 50; ++u) winl[csl[u]] += phi[u];
  }
  __syncthreads();
  if (tid < 80) {
    float wv = (tid < 77) ? winl[tid] : 0.f;
    P.WINH[cu*5120 + b*80 + tid] = (_Float16)wv;
  }
}

// y epilogue (batch b, step tt): identical math to round-5 kernel
__device__ __forceinline__ void yepi_do(const Params& P, float* rawl, float* smx, int b, int tt) {
  const int tid = threadIdx.x;
  if (tid < 121) rawl[tid] = P.GY[b*128 + tid];
  __syncthreads();
  const float bia = P.bias[b];
  if (tid == 0) {
    float m = -1e30f;
    for (int j = 1; j <= 20; ++j) m = fmaxf(m, rawl[j]*(1.f + bia));
    float ss = 0.f;
    for (int j = 1; j <= 20; ++j) ss += expf(rawl[j]*(1.f + bia) - m);
    smx[0] = m; smx[1] = ss;
  }
  __syncthreads();
  float* yr = P.out + ((size_t)b*NT + tt)*121;
  if (tid == 0)           yr[120] = 1.f/(1.f + expf(-rawl[0]));
  else if (tid <= 20)     yr[tid - 1] = expf(rawl[tid]*(1.f + bia) - smx[0]) / smx[1];
  else if (tid <= 60)     yr[80 + tid - 21] = rawl[tid];
  else if (tid <= 100)    yr[20 + tid - 61] = expf(rawl[tid] - bia);
  else if (tid <= 120)    yr[60 + tid - 101] = tanhf(rawl[tid]);
}

// =====================  persistent kernel: 224 WGs x 512 threads  =====================
__global__ __launch_bounds__(512, 1) void rnn_pers(Params P) {
  __shared__ __align__(16) char smem[105472];
  float* WtF  = (float*)smem;                 // mains: [2664][8] fp32 (85248 B); gmm: [1200][8]; att: WaF [12000]
  float* scrF = (float*)(smem + 85248);       // [8][64][8] f32 (16384 B)
  float* M    = (float*)(smem + 101632);
  float* bcl  = M;               // 24
  float* bgl  = M + 24;          // 8
  float* h1l  = M + 32;          // 400 (also yepi rawl)
  float* parts= M + 432;         // 240
  float* abk  = M + 672;         // 30
  float* kapl = M + 702;         // 10
  float* phi  = M + 712;         // 50
  float* winl = M + 762;         // 80
  float* batl = M + 842;         // 30
  float* smx  = M + 872;         // 2
  int*   csl  = (int*)(M + 874); // 50
  int*   cll  = (int*)(M + 924); // 1

  const int w = blockIdx.x, tid = threadIdx.x;
  int rlo = 0, nr = 0;

  // ---- one-time staging into LDS ----
  if (w < 200) {
    // weights, padded-concat [k][8] fp32
    for (int slot = 0; slot < 8; ++slot) {
      const int dd = slot >> 2, g = slot & 3, gr = g*400 + 2*w + dd;
      const float* ih1 = P.Wih1 + (size_t)gr*80;
      const float* hh1 = P.Whh1 + (size_t)gr*400;
      for (int k = tid; k < KP1; k += 512) {
        float v;
        if (k < 80)       v = (k < 77) ? ih1[k] : 0.f;
        else if (k < 88)  v = (k - 80 < 3) ? ih1[77 + (k - 80)] : 0.f;
        else              v = hh1[k - 88];
        WtF[BASE1 + k*8 + slot] = v;
      }
      const float* ih2 = P.Wih2 + (size_t)gr*480;
      const float* hh2 = P.Whh2 + (size_t)gr*400;
      for (int k = tid; k < KP2; k += 512) {
        float v;
        if (k < 8)        v = (k < 3) ? ih2[k] : 0.f;
        else if (k < 408) v = ih2[3 + (k - 8)];
        else if (k < 488) v = (k - 408 < 77) ? ih2[403 + (k - 408)] : 0.f;
        else              v = hh2[k - 488];
        WtF[BASE2 + k*8 + slot] = v;
      }
      const float* ih3 = P.Wih3 + (size_t)gr*880;
      const float* hh3 = P.Whh3 + (size_t)gr*400;
      for (int k = tid; k < KP3; k += 512) {
        float v;
        if (k < 8)        v = (k < 3) ? ih3[k] : 0.f;
        else if (k < 408) v = ih3[3 + (k - 8)];
        else if (k < 808) v = ih3[403 + (k - 408)];
        else if (k < 888) v = (k - 808 < 77) ? ih3[803 + (k - 808)] : 0.f;
        else              v = hh3[k - 888];
        WtF[BASE3 + k*8 + slot] = v;
      }
    }
    if (tid < 24) {
      int L = tid >> 3, slot = tid & 7, dd = slot >> 2, g = slot & 3;
      bcl[tid] = P.BC[L*1600 + g*400 + 2*w + dd];
    }
    if (w < 64) {
      // attention WGs overlay Watt into the (unused) upper WtF region? No -- mains use WtF.
      // att WGs (w<64) ARE main WGs here; Watt goes to a global-read fallback? No:
      // att WGs need Watt in LDS but also their main weights. Use scrF-adjacent? Not enough.
      // -> att reads Watt from global would re-add redundancy. Instead: Watt rows cached
      //    per-WG in the 240-thread loop via __ldg (12000 f32 = 48KB per step from L2).
      // Keep LDS staging of batl/csl/cll only.
      if (tid < 30) batl[tid] = P.batt[tid];
      if (tid < 50) csl[tid] = P.cs[w*50 + tid];
      if (tid == 0) cll[0] = P.cl[w];
    }
  } else {
    int q = w - 200;
    rlo = (121*q)/24;
    nr  = (121*(q+1))/24 - rlo;
    for (int j = 0; j < 8; ++j)
      for (int k = tid; k < 1200; k += 512)
        WtF[k*8 + j] = (j < nr) ? P.Wgmm[(size_t)(rlo + j)*1200 + k] : 0.f;
    if (tid < 8) bgl[tid] = (tid < nr) ? P.bgmm[rlo + tid] : 0.f;
  }
  __syncthreads();

  int ph = 0;
  float c1 = 0.f, c2 = 0.f, c3 = 0.f;
  for (int t = 0; t <= NT; ++t) {
    // P1: L1(t) on mains || GMM(t-1) on WGs 200..223
    if (w < 200) { if (t < NT) lphase<0>(P, WtF, scrF, bcl, w, t, c1); }
    else if (t >= 1) gmm_do(P, WtF, scrF, bgl, rlo, nr, t - 1);
    tbar(P.CNT, w & 7, ph);
    // P2: att(t) on w<64 || y-epilogue(t-1) on w in [64,128)
    if (w < 64) { if (t < NT) att_do(P, P.Watt, h1l, parts, abk, kapl, phi, winl, batl, csl, cll, w, t); }
    else if (w < 128) { if (t >= 1) yepi_do(P, h1l, smx, w - 64, t - 1); }
    tbar(P.CNT, w & 7, ph);
    if (t == NT) break;
    // P3: L2(t)
    if (w < 200) lphase<1>(P, WtF, scrF, bcl, w, t, c2);
    tbar(P.CNT, w & 7, ph);
    // P4: L3(t)
    if (w < 200) lphase<2>(P, WtF, scrF, bcl, w, t, c3);
    tbar(P.CNT, w & 7, ph);
  }
}

extern "C" void kernel_launch(void* const* d_in, const int* in_sizes, int n_in,
                              void* d_out, int out_size, void* d_ws, size_t ws_size,
                              hipStream_t stream) {
  (void)in_sizes; (void)n_in; (void)out_size; (void)ws_size;
  Params P;
  P.x    = (const float*)d_in[0];
  P.cs   = (const int*)d_in[1];
  P.cl   = (const int*)d_in[2];
  P.bias = (const float*)d_in[3];
  P.Wih1 = (const float*)d_in[4];  P.Whh1 = (const float*)d_in[5];
  P.bih1 = (const float*)d_in[6];  P.bhh1 = (const float*)d_in[7];
  P.Wih2 = (const float*)d_in[8];  P.Whh2 = (const float*)d_in[9];
  P.bih2 = (const float*)d_in[10]; P.bhh2 = (const float*)d_in[11];
  P.Wih3 = (const float*)d_in[12]; P.Whh3 = (const float*)d_in[13];
  P.bih3 = (const float*)d_in[14]; P.bhh3 = (const float*)d_in[15];
  P.Watt = (const float*)d_in[16]; P.batt = (const float*)d_in[17];
  P.Wgmm = (const float*)d_in[18]; P.bgmm = (const float*)d_in[19];
  char* ws = (char*)d_ws;
  P.XTH  = (_Float16*)(ws + OFF_XTH);
  P.H1F  = (float*)(ws + OFF_H1F);
  P.H1H  = (_Float16*)(ws + OFF_H1H);
  P.H2H  = (_Float16*)(ws + OFF_H2H);
  P.H3H  = (_Float16*)(ws + OFF_H3H);
  P.WINH = (_Float16*)(ws + OFF_WINH);
  P.KAP  = (float*)(ws + OFF_KAP);
  P.BC   = (float*)(ws + OFF_BC);
  P.GY   = (float*)(ws + OFF_GY);
  P.CNT  = (int*)(ws + OFF_CNT);
  P.out  = (float*)d_out;

  hipLaunchKernelGGL(prep_k, dim3(1024), dim3(256), 0, stream, P);
  hipLaunchKernelGGL(rnn_pers, dim3(224), dim3(512), 0, stream, P);
}

// Round 7
// 34569.965 us; speedup vs baseline: 7.4880x; 1.1193x over previous
//
#include <hip/hip_runtime.h>
#include <stdint.h>

#define NT 600

// ---- ws layout (bytes) ----
#define OFF_XTH  0          // [600][64][8]  f16   614400
#define OFF_H1H  614400     // [2][64][400]  f16   102400
#define OFF_H2H  716800     // [2][64][400]  f16   102400
#define OFF_H3H  819200     // [2][64][400]  f16   102400
#define OFF_WINH 921600     // [2][64][80]   f16   20480
#define OFF_BC   942080     // [3][1600]     f32   19200
#define OFF_GY   961280     // [64][128]     f32   32768
#define OFF_CNT  994048     // [8*16]        i32   512

// padded K layouts (every segment a multiple of 8), in 8-k "chunks"
// L1: win(10) x(1) h1(50)            = 61 chunks  (KP1=488)
// L2: x(1) h1(50) win(10) h2(50)     = 111 chunks (KP2=888)
// L3: x(1) h1(50) h2(50) win(10) h3(50) = 161 chunks (KP3=1288)
#define KP1 488
#define KP2 888
#define KP3 1288
#define CB1 0
#define CB2 61
#define CB3 172
// main LDS weight store: 333 chunks x 64 f16 = 21312 f16 = 42624 B

typedef float f32x4 __attribute__((ext_vector_type(4)));
typedef _Float16 h2 __attribute__((ext_vector_type(2)));

struct Params {
  const float* x; const int* cs; const int* cl; const float* bias;
  const float *Wih1,*Whh1,*bih1,*bhh1,*Wih2,*Whh2,*bih2,*bhh2,*Wih3,*Whh3,*bih3,*bhh3;
  const float *Watt,*batt,*Wgmm,*bgmm;
  _Float16 *XTH,*H1H,*H2H,*H3H,*WINH;
  float *BC,*GY;
  int *CNT;
  float* out;
};

__device__ __forceinline__ float sigm(float x) { return 1.f / (1.f + expf(-x)); }

__device__ __forceinline__ float FDOT2(unsigned a, unsigned b, float c) {
#if __has_builtin(__builtin_amdgcn_fdot2)
  return __builtin_amdgcn_fdot2(__builtin_bit_cast(h2, a), __builtin_bit_cast(h2, b), c, false);
#else
  h2 x = __builtin_bit_cast(h2, a), y = __builtin_bit_cast(h2, b);
  return c + (float)x[0]*(float)y[0] + (float)x[1]*(float)y[1];
#endif
}

// 8-sub-counter barrier over 224 WGs (28 per sub-counter)
__device__ __forceinline__ void tbar(int* C, int wmod, int& ph) {
  __syncthreads();
  if (threadIdx.x == 0)
    __hip_atomic_fetch_add(&C[wmod*16], 1, __ATOMIC_RELEASE, __HIP_MEMORY_SCOPE_AGENT);
  ++ph;
  const int tgt = 28*ph;
  if (threadIdx.x < 8) {
    while (__hip_atomic_load(&C[threadIdx.x*16], __ATOMIC_RELAXED, __HIP_MEMORY_SCOPE_AGENT) < tgt)
      __builtin_amdgcn_s_sleep(1);
    (void)__hip_atomic_load(&C[threadIdx.x*16], __ATOMIC_ACQUIRE, __HIP_MEMORY_SCOPE_AGENT);
  }
  __syncthreads();
}

// =====================  prep  =====================
__global__ void prep_k(Params P) {
  const long long NX  = 600LL*512;
  const long long NHH = 51200;
  const long long NWH = 10240;
  const long long NBc = 4800;
  const long long NCt = 128;
  const long long TOT = NX + 3*NHH + NWH + NBc + NCt;
  const long long stride = (long long)gridDim.x * blockDim.x;
  for (long long idx = (long long)blockIdx.x*blockDim.x + threadIdx.x; idx < TOT; idx += stride) {
    long long i = idx;
    if (i < NX) {
      int t = (int)(i >> 9);
      int rem = (int)(i & 511);
      int b = rem >> 3, k = rem & 7;
      float v = (k < 3) ? P.x[((size_t)b*NT + t)*3 + k] : 0.f;
      P.XTH[i] = (_Float16)v;
      continue;
    }
    i -= NX;
    if (i < NHH) { P.H1H[i] = (_Float16)0.f; continue; } i -= NHH;
    if (i < NHH) { P.H2H[i] = (_Float16)0.f; continue; } i -= NHH;
    if (i < NHH) { P.H3H[i] = (_Float16)0.f; continue; } i -= NHH;
    if (i < NWH) { P.WINH[i] = (_Float16)0.f; continue; } i -= NWH;
    if (i < NBc) {
      int l = (int)(i / 1600), r = (int)(i % 1600);
      const float* bi = (l==0)?P.bih1:(l==1)?P.bih2:P.bih3;
      const float* bh = (l==0)?P.bhh1:(l==1)?P.bhh2:P.bhh3;
      P.BC[i] = bi[r] + bh[r];
      continue;
    }
    i -= NBc;
    P.CNT[i] = 0;
  }
}

// =====================  LSTM phase =====================
// WG w<200 owns dims {2w,2w+1} = 8 gate rows (slot = dd*4+g). 8 waves split k-chunks.
template<int L>
__device__ __forceinline__ void lphase(const Params& P, const uint4* W4, float* scrF,
                                       const float* bcl, int w, int t, float& cref) {
  const int tid = threadIdx.x, ks = tid >> 6, b = tid & 63;
  const int cu = t & 1, pv = (t + 1) & 1;
  const _Float16* sp[5]; int nch[5], rl[5]; int ns;
  if (L == 0) {
    sp[0] = P.WINH + pv*5120;  nch[0] = 10; rl[0] = 80;
    sp[1] = P.XTH + t*512;     nch[1] = 1;  rl[1] = 8;
    sp[2] = P.H1H + pv*25600;  nch[2] = 50; rl[2] = 400;
    ns = 3;
  } else if (L == 1) {
    sp[0] = P.XTH + t*512;     nch[0] = 1;  rl[0] = 8;
    sp[1] = P.H1H + cu*25600;  nch[1] = 50; rl[1] = 400;
    sp[2] = P.WINH + cu*5120;  nch[2] = 10; rl[2] = 80;
    sp[3] = P.H2H + pv*25600;  nch[3] = 50; rl[3] = 400;
    ns = 4;
  } else {
    sp[0] = P.XTH + t*512;     nch[0] = 1;  rl[0] = 8;
    sp[1] = P.H1H + cu*25600;  nch[1] = 50; rl[1] = 400;
    sp[2] = P.H2H + cu*25600;  nch[2] = 50; rl[2] = 400;
    sp[3] = P.WINH + cu*5120;  nch[3] = 10; rl[3] = 80;
    sp[4] = P.H3H + pv*25600;  nch[4] = 50; rl[4] = 400;
    ns = 5;
  }
  float ac[8] = {0.f,0.f,0.f,0.f,0.f,0.f,0.f,0.f};
  int cb = (L==0) ? CB1 : (L==1) ? CB2 : CB3;
  for (int s = 0; s < ns; ++s) {
    const _Float16* p = sp[s] + (size_t)b*rl[s];
    const uint4* wb = W4 + (size_t)cb*8;
    for (int c = ks; c < nch[s]; c += 8) {
      uint4 sv = *(const uint4*)(p + (size_t)c*8);
      const uint4* wc = wb + (size_t)c*8;
#pragma unroll
      for (int j = 0; j < 8; ++j) {
        uint4 wv = wc[j];
        float a = ac[j];
        a = FDOT2(sv.x, wv.x, a);
        a = FDOT2(sv.y, wv.y, a);
        a = FDOT2(sv.z, wv.z, a);
        a = FDOT2(sv.w, wv.w, a);
        ac[j] = a;
      }
    }
    cb += nch[s];
  }
#pragma unroll
  for (int j = 0; j < 8; ++j) scrF[(ks*64 + b)*8 + j] = ac[j];
  __syncthreads();
  const int r = tid & 7;
  float D = 0.f;
#pragma unroll
  for (int k = 0; k < 8; ++k) D += scrF[k*512 + tid];
  D += bcl[L*8 + r];
  float v1 = __shfl_xor(D, 1);
  float v2 = __shfl_xor(D, 2);
  float v3 = __shfl_xor(D, 3);
  if ((tid & 3) == 0) {   // r in {0,4}: gates (i,f,g,o) = (D,v1,v2,v3)
    float c = sigm(v1)*cref + sigm(D)*tanhf(v2);
    cref = c;
    float h = sigm(v3)*tanhf(c);
    const int dd = r >> 2, b2 = tid >> 3, d = 2*w + dd;
    _Float16* HH = (L==0) ? P.H1H : (L==1) ? P.H2H : P.H3H;
    HH[cu*25600 + b2*400 + d] = (_Float16)h;
  }
}

// GMM raw rows rlo..rlo+nr-1 for step tt -> GY[b][r]
__device__ __forceinline__ void gmm_do(const Params& P, const uint4* W4, float* scrF,
                                       const float* bgl, int rlo, int nr, int tt) {
  const int tid = threadIdx.x, ks = tid >> 6, b = tid & 63, cu = tt & 1;
  const _Float16* sp[3] = {P.H1H + cu*25600, P.H2H + cu*25600, P.H3H + cu*25600};
  float ac[8] = {0.f,0.f,0.f,0.f,0.f,0.f,0.f,0.f};
  for (int s = 0; s < 3; ++s) {
    const _Float16* p = sp[s] + (size_t)b*400;
    const uint4* wb = W4 + (size_t)(s*50)*8;
    for (int c = ks; c < 50; c += 8) {
      uint4 sv = *(const uint4*)(p + (size_t)c*8);
      const uint4* wc = wb + (size_t)c*8;
#pragma unroll
      for (int j = 0; j < 8; ++j) {
        uint4 wv = wc[j];
        float a = ac[j];
        a = FDOT2(sv.x, wv.x, a);
        a = FDOT2(sv.y, wv.y, a);
        a = FDOT2(sv.z, wv.z, a);
        a = FDOT2(sv.w, wv.w, a);
        ac[j] = a;
      }
    }
  }
#pragma unroll
  for (int j = 0; j < 8; ++j) scrF[(ks*64 + b)*8 + j] = ac[j];
  __syncthreads();
  const int r = tid & 7, b2 = tid >> 3;
  float D = 0.f;
#pragma unroll
  for (int k = 0; k < 8; ++k) D += scrF[k*512 + tid];
  if (r < nr) P.GY[b2*128 + rlo + r] = D + bgl[r];
}

// attention window (batch b); Watt f16-pairs in LDS, kappa persistent in LDS
__device__ __forceinline__ void att_do(const Params& P, const unsigned* WAPH, unsigned* h1p,
    float* parts, float* abk, float* kapl, float* phi, float* winl,
    const float* batl, const int* csl, const int* cll, int b, int t) {
  const int tid = threadIdx.x, cu = t & 1;
  if (tid < 200) h1p[tid] = ((const unsigned*)(P.H1H + cu*25600 + (size_t)b*400))[tid];
  if (tid < 80) winl[tid] = 0.f;
  __syncthreads();
  if (tid < 240) {
    int j = tid >> 3, pp = tid & 7;
    const unsigned* wr = WAPH + j*200 + pp*25;
    const unsigned* hr = h1p + pp*25;
    float acc = 0.f;
#pragma unroll
    for (int m = 0; m < 25; ++m) acc = FDOT2(hr[m], wr[m], acc);
    parts[tid] = acc;
  }
  __syncthreads();
  if (tid < 30) {
    float s = batl[tid];
#pragma unroll
    for (int pp = 0; pp < 8; ++pp) s += parts[tid*8 + pp];
    abk[tid] = expf(s);
  }
  __syncthreads();
  if (tid < 10) kapl[tid] = kapl[tid] + abk[20 + tid];
  __syncthreads();
  if (tid < 50) {
    float s = 0.f;
    if (tid < cll[0]) {
#pragma unroll
      for (int k = 0; k < 10; ++k) {
        float dk = kapl[k] - (float)tid;
        s += abk[k]*expf(-abk[10 + k]*dk*dk);
      }
    }
    phi[tid] = s;
  }
  __syncthreads();
  if (tid == 0) {
    for (int u = 0; u < 50; ++u) winl[csl[u]] += phi[u];
  }
  __syncthreads();
  if (tid < 80) {
    float wv = (tid < 77) ? winl[tid] : 0.f;
    P.WINH[cu*5120 + b*80 + tid] = (_Float16)wv;
  }
}

// y epilogue (batch b, step tt)
__device__ __forceinline__ void yepi_do(const Params& P, float* rawl, float* smx, int b, int tt) {
  const int tid = threadIdx.x;
  if (tid < 121) rawl[tid] = P.GY[b*128 + tid];
  __syncthreads();
  const float bia = P.bias[b];
  if (tid == 0) {
    float m = -1e30f;
    for (int j = 1; j <= 20; ++j) m = fmaxf(m, rawl[j]*(1.f + bia));
    float ss = 0.f;
    for (int j = 1; j <= 20; ++j) ss += expf(rawl[j]*(1.f + bia) - m);
    smx[0] = m; smx[1] = ss;
  }
  __syncthreads();
  float* yr = P.out + ((size_t)b*NT + tt)*121;
  if (tid == 0)           yr[120] = 1.f/(1.f + expf(-rawl[0]));
  else if (tid <= 20)     yr[tid - 1] = expf(rawl[tid]*(1.f + bia) - smx[0]) / smx[1];
  else if (tid <= 60)     yr[80 + tid - 21] = rawl[tid];
  else if (tid <= 100)    yr[20 + tid - 61] = expf(rawl[tid] - bia);
  else if (tid <= 120)    yr[60 + tid - 101] = tanhf(rawl[tid]);
}

// =====================  persistent kernel: 224 WGs x 512 threads  =====================
__global__ __launch_bounds__(512, 1) void rnn_pers(Params P) {
  __shared__ __align__(16) char smem[88576];
  _Float16* WH16 = (_Float16*)smem;            // mains: 333 chunks x 64 f16 (42624 B); gmm: 150 x 64
  const uint4* W4 = (const uint4*)smem;
  float* scrF = (float*)(smem + 42624);        // [8][64][8] f32 (16384 B)
  unsigned* WAPH = (unsigned*)(smem + 59008);  // att (w<64): Watt f16 pairs [30][200] (24000 B)
  float* M    = (float*)(smem + 83008);
  float* bcl  = M;                // 24
  float* bgl  = M + 24;           // 8
  float* parts= M + 32;           // 240
  float* abk  = M + 272;          // 30
  float* kapl = M + 302;          // 10  (persistent kappa)
  float* phi  = M + 312;          // 50
  float* winl = M + 362;          // 80
  float* batl = M + 442;          // 30
  float* rawl = M + 472;          // 121 (yepi)
  float* smx  = M + 593;          // 2
  unsigned* h1p = (unsigned*)(M + 595); // 200
  int*   csl  = (int*)(M + 795);  // 50
  int*   cll  = (int*)(M + 845);  // 1

  const int w = blockIdx.x, tid = threadIdx.x;
  int rlo = 0, nr = 0;

  // ---- one-time staging into LDS ----
  if (w < 200) {
    for (int slot = 0; slot < 8; ++slot) {
      const int dd = slot >> 2, g = slot & 3, gr = g*400 + 2*w + dd;
      const float* ih1 = P.Wih1 + (size_t)gr*80;
      const float* hh1 = P.Whh1 + (size_t)gr*400;
      for (int k = tid; k < KP1; k += 512) {
        float v;
        if (k < 80)       v = (k < 77) ? ih1[k] : 0.f;
        else if (k < 88)  v = (k - 80 < 3) ? ih1[77 + (k - 80)] : 0.f;
        else              v = hh1[k - 88];
        WH16[(CB1 + (k>>3))*64 + slot*8 + (k&7)] = (_Float16)v;
      }
      const float* ih2 = P.Wih2 + (size_t)gr*480;
      const float* hh2 = P.Whh2 + (size_t)gr*400;
      for (int k = tid; k < KP2; k += 512) {
        float v;
        if (k < 8)        v = (k < 3) ? ih2[k] : 0.f;
        else if (k < 408) v = ih2[3 + (k - 8)];
        else if (k < 488) v = (k - 408 < 77) ? ih2[403 + (k - 408)] : 0.f;
        else              v = hh2[k - 488];
        WH16[(CB2 + (k>>3))*64 + slot*8 + (k&7)] = (_Float16)v;
      }
      const float* ih3 = P.Wih3 + (size_t)gr*880;
      const float* hh3 = P.Whh3 + (size_t)gr*400;
      for (int k = tid; k < KP3; k += 512) {
        float v;
        if (k < 8)        v = (k < 3) ? ih3[k] : 0.f;
        else if (k < 408) v = ih3[3 + (k - 8)];
        else if (k < 808) v = ih3[403 + (k - 408)];
        else if (k < 888) v = (k - 808 < 77) ? ih3[803 + (k - 808)] : 0.f;
        else              v = hh3[k - 888];
        WH16[(CB3 + (k>>3))*64 + slot*8 + (k&7)] = (_Float16)v;
      }
    }
    if (tid < 24) {
      int L = tid >> 3, slot = tid & 7, dd = slot >> 2, g = slot & 3;
      bcl[tid] = P.BC[L*1600 + g*400 + 2*w + dd];
    }
    if (w < 64) {
      for (int i = tid; i < 6000; i += 512) {
        int j = i / 200, pr = i % 200;
        h2 pk = { (_Float16)P.Watt[j*400 + 2*pr], (_Float16)P.Watt[j*400 + 2*pr + 1] };
        WAPH[i] = __builtin_bit_cast(unsigned, pk);
      }
      if (tid < 30) batl[tid] = P.batt[tid];
      if (tid < 50) csl[tid] = P.cs[w*50 + tid];
      if (tid == 0) cll[0] = P.cl[w];
      if (tid < 10) kapl[tid] = 0.f;
    }
  } else {
    int q = w - 200;
    rlo = (121*q)/24;
    nr  = (121*(q+1))/24 - rlo;
    for (int j = 0; j < 8; ++j)
      for (int k = tid; k < 1200; k += 512)
        WH16[(k>>3)*64 + j*8 + (k&7)] = (_Float16)((j < nr) ? P.Wgmm[(size_t)(rlo + j)*1200 + k] : 0.f);
    if (tid < 8) bgl[tid] = (tid < nr) ? P.bgmm[rlo + tid] : 0.f;
  }
  __syncthreads();

  int ph = 0;
  float c1 = 0.f, c2 = 0.f, c3 = 0.f;
  for (int t = 0; t <= NT; ++t) {
    // P1: L1(t) on mains || GMM(t-1) on WGs 200..223
    if (w < 200) { if (t < NT) lphase<0>(P, W4, scrF, bcl, w, t, c1); }
    else if (t >= 1) gmm_do(P, W4, scrF, bgl, rlo, nr, t - 1);
    tbar(P.CNT, w & 7, ph);
    // P2: att(t) on w<64 || y-epilogue(t-1) on w in [64,128)
    if (w < 64) { if (t < NT) att_do(P, WAPH, h1p, parts, abk, kapl, phi, winl, batl, csl, cll, w, t); }
    else if (w < 128) { if (t >= 1) yepi_do(P, rawl, smx, w - 64, t - 1); }
    tbar(P.CNT, w & 7, ph);
    if (t == NT) break;
    // P3: L2(t)
    if (w < 200) lphase<1>(P, W4, scrF, bcl, w, t, c2);
    tbar(P.CNT, w & 7, ph);
    // P4: L3(t)
    if (w < 200) lphase<2>(P, W4, scrF, bcl, w, t, c3);
    tbar(P.CNT, w & 7, ph);
  }
}

extern "C" void kernel_launch(void* const* d_in, const int* in_sizes, int n_in,
                              void* d_out, int out_size, void* d_ws, size_t ws_size,
                              hipStream_t stream) {
  (void)in_sizes; (void)n_in; (void)out_size; (void)ws_size;
  Params P;
  P.x    = (const float*)d_in[0];
  P.cs   = (const int*)d_in[1];
  P.cl   = (const int*)d_in[2];
  P.bias = (const float*)d_in[3];
  P.Wih1 = (const float*)d_in[4];  P.Whh1 = (const float*)d_in[5];
  P.bih1 = (const float*)d_in[6];  P.bhh1 = (const float*)d_in[7];
  P.Wih2 = (const float*)d_in[8];  P.Whh2 = (const float*)d_in[9];
  P.bih2 = (const float*)d_in[10]; P.bhh2 = (const float*)d_in[11];
  P.Wih3 = (const float*)d_in[12]; P.Whh3 = (const float*)d_in[13];
  P.bih3 = (const float*)d_in[14]; P.bhh3 = (const float*)d_in[15];
  P.Watt = (const float*)d_in[16]; P.batt = (const float*)d_in[17];
  P.Wgmm = (const float*)d_in[18]; P.bgmm = (const float*)d_in[19];
  char* ws = (char*)d_ws;
  P.XTH  = (_Float16*)(ws + OFF_XTH);
  P.H1H  = (_Float16*)(ws + OFF_H1H);
  P.H2H  = (_Float16*)(ws + OFF_H2H);
  P.H3H  = (_Float16*)(ws + OFF_H3H);
  P.WINH = (_Float16*)(ws + OFF_WINH);
  P.BC   = (float*)(ws + OFF_BC);
  P.GY   = (float*)(ws + OFF_GY);
  P.CNT  = (int*)(ws + OFF_CNT);
  P.out  = (float*)d_out;

  hipLaunchKernelGGL(prep_k, dim3(1024), dim3(256), 0, stream, P);
  hipLaunchKernelGGL(rnn_pers, dim3(224), dim3(512), 0, stream, P);
}

// Round 8
// 33758.963 us; speedup vs baseline: 7.6679x; 1.0240x over previous
//
#include <hip/hip_runtime.h>
#include <stdint.h>

#define NT 600

// ---- ws layout (bytes) ----
#define OFF_XTH  0          // [600][64][8]  f16   614400
#define OFF_H1H  614400     // [2][64][400]  f16   102400
#define OFF_H2H  716800     // [2][64][400]  f16   102400
#define OFF_H3H  819200     // [2][64][400]  f16   102400
#define OFF_WINH 921600     // [2][64][80]   f16   20480
#define OFF_BC   942080     // [3][1600]     f32   19200
#define OFF_GY   961280     // [64][128]     f32   32768
#define OFF_CNT  994048     // [16*32]       i32   2048

// chunk layout (8-k chunks of 8 slots x 8 f16 = 128B each)
// L1 @0:   win(10) x(1) h1(50)                      = 61
// L2 @61:  x(1) h1(50) h2prev(50) win(10)           = 111   (partial=101, finish=10)
// L3 @172: x(1) h1(50) h3prev(50) h2cur(50) win(10) = 161   (partial=101, finish=60)
#define NMAIN 200
#define NAUX  56
#define NWG   256
#define NSUB  16

typedef _Float16 h2v __attribute__((ext_vector_type(2)));

struct Params {
  const float* x; const int* cs; const int* cl; const float* bias;
  const float *Wih1,*Whh1,*bih1,*bhh1,*Wih2,*Whh2,*bih2,*bhh2,*Wih3,*Whh3,*bih3,*bhh3;
  const float *Watt,*batt,*Wgmm,*bgmm;
  _Float16 *XTH,*H1H,*H2H,*H3H,*WINH;
  float *BC,*GY;
  int *CNT;
  float* out;
};

__device__ __forceinline__ float sigm(float x) { return 1.f / (1.f + expf(-x)); }

__device__ __forceinline__ float FDOT2(unsigned a, unsigned b, float c) {
#if __has_builtin(__builtin_amdgcn_fdot2)
  return __builtin_amdgcn_fdot2(__builtin_bit_cast(h2v, a), __builtin_bit_cast(h2v, b), c, false);
#else
  h2v x = __builtin_bit_cast(h2v, a), y = __builtin_bit_cast(h2v, b);
  return c + (float)x[0]*(float)y[0] + (float)x[1]*(float)y[1];
#endif
}

// 16-sub-counter barrier over 256 WGs (16 per sub-counter)
__device__ __forceinline__ void tbar(int* C, int w, int& ph) {
  __syncthreads();
  if (threadIdx.x == 0)
    __hip_atomic_fetch_add(&C[(w & 15)*32], 1, __ATOMIC_RELEASE, __HIP_MEMORY_SCOPE_AGENT);
  ++ph;
  const int tgt = 16*ph;
  if (threadIdx.x < 16) {
    while (__hip_atomic_load(&C[threadIdx.x*32], __ATOMIC_RELAXED, __HIP_MEMORY_SCOPE_AGENT) < tgt)
      __builtin_amdgcn_s_sleep(1);
    (void)__hip_atomic_load(&C[threadIdx.x*32], __ATOMIC_ACQUIRE, __HIP_MEMORY_SCOPE_AGENT);
  }
  __syncthreads();
}

// =====================  prep  =====================
__global__ void prep_k(Params P) {
  const long long NX  = 600LL*512;
  const long long NHH = 51200;
  const long long NWH = 10240;
  const long long NBc = 4800;
  const long long NCt = 512;
  const long long TOT = NX + 3*NHH + NWH + NBc + NCt;
  const long long stride = (long long)gridDim.x * blockDim.x;
  for (long long idx = (long long)blockIdx.x*blockDim.x + threadIdx.x; idx < TOT; idx += stride) {
    long long i = idx;
    if (i < NX) {
      int t = (int)(i >> 9);
      int rem = (int)(i & 511);
      int b = rem >> 3, k = rem & 7;
      float v = (k < 3) ? P.x[((size_t)b*NT + t)*3 + k] : 0.f;
      P.XTH[i] = (_Float16)v;
      continue;
    }
    i -= NX;
    if (i < NHH) { P.H1H[i] = (_Float16)0.f; continue; } i -= NHH;
    if (i < NHH) { P.H2H[i] = (_Float16)0.f; continue; } i -= NHH;
    if (i < NHH) { P.H3H[i] = (_Float16)0.f; continue; } i -= NHH;
    if (i < NWH) { P.WINH[i] = (_Float16)0.f; continue; } i -= NWH;
    if (i < NBc) {
      int l = (int)(i / 1600), r = (int)(i % 1600);
      const float* bi = (l==0)?P.bih1:(l==1)?P.bih2:P.bih3;
      const float* bh = (l==0)?P.bhh1:(l==1)?P.bhh2:P.bhh3;
      P.BC[i] = bi[r] + bh[r];
      continue;
    }
    i -= NBc;
    P.CNT[i] = 0;
  }
}

// accumulate one source segment into ac[8], 1-deep prefetch of the next chunk
__device__ __forceinline__ void lacc_seg(float (&ac)[8], const uint4* W4, int cb,
    const _Float16* src, int nch, int rl, int b, int ks) {
  const _Float16* p = src + (size_t)b*rl;
  const uint4* wb = W4 + (size_t)cb*8;
  int c = ks;
  if (c >= nch) return;
  uint4 sv = *(const uint4*)(p + (size_t)c*8);
  while (true) {
    const int c2 = c + 8;
    const bool more = c2 < nch;
    uint4 nx;
    if (more) nx = *(const uint4*)(p + (size_t)c2*8);
    const uint4* wc = wb + (size_t)c*8;
#pragma unroll
    for (int j = 0; j < 8; ++j) {
      uint4 wv = wc[j];
      float a = ac[j];
      a = FDOT2(sv.x, wv.x, a);
      a = FDOT2(sv.y, wv.y, a);
      a = FDOT2(sv.z, wv.z, a);
      a = FDOT2(sv.w, wv.w, a);
      ac[j] = a;
    }
    if (!more) break;
    c = c2; sv = nx;
  }
}

// reduce 8-wave partials, LSTM nonlinearity, packed u32 h-write
__device__ __forceinline__ void lfinish(float (&ac)[8], float* scrF, const float* bcl,
    int Lidx, _Float16* HH, int cu, int w, float& cref) {
  const int tid = threadIdx.x, ks = tid >> 6, b = tid & 63;
#pragma unroll
  for (int j = 0; j < 8; ++j) scrF[(ks*64 + b)*8 + j] = ac[j];
  __syncthreads();
  const int r = tid & 7;
  float D = 0.f;
#pragma unroll
  for (int k = 0; k < 8; ++k) D += scrF[k*512 + tid];
  D += bcl[Lidx*8 + r];
  float v1 = __shfl_xor(D, 1);
  float v2 = __shfl_xor(D, 2);
  float v3 = __shfl_xor(D, 3);
  if ((tid & 3) == 0) {   // r in {0,4}: gates (i,f,g,o) = (D,v1,v2,v3)
    float c = sigm(v1)*cref + sigm(D)*tanhf(v2);
    cref = c;
    float h = sigm(v3)*tanhf(c);
    unsigned hu = (unsigned)__builtin_bit_cast(unsigned short, (_Float16)h);
    unsigned other = (unsigned)__shfl_xor((int)hu, 4);
    if (r == 0) {
      const int b2 = tid >> 3;
      unsigned pk = hu | (other << 16);   // [2w] lo, [2w+1] hi
      *(unsigned*)(HH + (size_t)cu*25600 + (size_t)b2*400 + 2*w) = pk;
    }
  }
}

// GMM rows rlo..rlo+nr-1 for step tt -> GY[b][r]
__device__ __forceinline__ void gmm_do(const Params& P, const uint4* W4, float* scrF,
                                       const float* bgl, int rlo, int nr, int tt) {
  const int tid = threadIdx.x, ks = tid >> 6, b = tid & 63, cuu = tt & 1;
  float ac[8] = {0.f,0.f,0.f,0.f,0.f,0.f,0.f,0.f};
  lacc_seg(ac, W4, 0,   P.H1H + (size_t)cuu*25600, 50, 400, b, ks);
  lacc_seg(ac, W4, 50,  P.H2H + (size_t)cuu*25600, 50, 400, b, ks);
  lacc_seg(ac, W4, 100, P.H3H + (size_t)cuu*25600, 50, 400, b, ks);
#pragma unroll
  for (int j = 0; j < 8; ++j) scrF[(ks*64 + b)*8 + j] = ac[j];
  __syncthreads();
  const int r = tid & 7, b2 = tid >> 3;
  float D = 0.f;
#pragma unroll
  for (int k = 0; k < 8; ++k) D += scrF[k*512 + tid];
  if (r < nr) P.GY[b2*128 + rlo + r] = D + bgl[r];
}

// attention window for batch b (local slot lb)
__device__ __forceinline__ void att_do(const Params& P, const unsigned* WAPH, unsigned* h1p,
    float* parts, float* abk, float* kapl, float* phi, float* winl,
    const float* batl, const int* csl, const int* cll, int b, int lb, int t) {
  const int tid = threadIdx.x, cu = t & 1;
  if (tid < 200) h1p[tid] = ((const unsigned*)(P.H1H + (size_t)cu*25600 + (size_t)b*400))[tid];
  if (tid < 80) winl[tid] = 0.f;
  __syncthreads();
  if (tid < 240) {
    int j = tid >> 3, pp = tid & 7;
    const unsigned* wr = WAPH + j*200 + pp*25;
    const unsigned* hr = h1p + pp*25;
    float acc = 0.f;
#pragma unroll
    for (int m = 0; m < 25; ++m) acc = FDOT2(hr[m], wr[m], acc);
    parts[tid] = acc;
  }
  __syncthreads();
  if (tid < 30) {
    float s = batl[tid];
#pragma unroll
    for (int pp = 0; pp < 8; ++pp) s += parts[tid*8 + pp];
    abk[tid] = expf(s);
  }
  __syncthreads();
  if (tid < 10) kapl[lb*10 + tid] += abk[20 + tid];
  __syncthreads();
  if (tid < 50) {
    float s = 0.f;
    if (tid < cll[lb]) {
#pragma unroll
      for (int k = 0; k < 10; ++k) {
        float dk = kapl[lb*10 + k] - (float)tid;
        s += abk[k]*expf(-abk[10 + k]*dk*dk);
      }
    }
    phi[tid] = s;
  }
  __syncthreads();
  if (tid == 0) {
    for (int u = 0; u < 50; ++u) winl[csl[lb*50 + u]] += phi[u];
  }
  __syncthreads();
  if (tid < 40)
    *(unsigned*)(P.WINH + (size_t)cu*5120 + (size_t)b*80 + 2*tid) =
      __builtin_bit_cast(unsigned, (h2v){ (_Float16)((2*tid < 77) ? winl[2*tid] : 0.f),
                                          (_Float16)((2*tid+1 < 77) ? winl[2*tid+1] : 0.f) });
  __syncthreads();
}

// y epilogue for batch b, step tt
__device__ __forceinline__ void yepi_do(const Params& P, float* rawl, float* smx, int b, int tt) {
  const int tid = threadIdx.x;
  if (tid < 121) rawl[tid] = P.GY[b*128 + tid];
  __syncthreads();
  const float bia = P.bias[b];
  if (tid == 0) {
    float m = -1e30f;
    for (int j = 1; j <= 20; ++j) m = fmaxf(m, rawl[j]*(1.f + bia));
    float ss = 0.f;
    for (int j = 1; j <= 20; ++j) ss += expf(rawl[j]*(1.f + bia) - m);
    smx[0] = m; smx[1] = ss;
  }
  __syncthreads();
  float* yr = P.out + ((size_t)b*NT + tt)*121;
  if (tid == 0)           yr[120] = 1.f/(1.f + expf(-rawl[0]));
  else if (tid <= 20)     yr[tid - 1] = expf(rawl[tid]*(1.f + bia) - smx[0]) / smx[1];
  else if (tid <= 60)     yr[80 + tid - 21] = rawl[tid];
  else if (tid <= 100)    yr[20 + tid - 61] = expf(rawl[tid] - bia);
  else if (tid <= 120)    yr[60 + tid - 101] = tanhf(rawl[tid]);
  __syncthreads();
}

// =====================  persistent kernel: 256 WGs x 512 threads  =====================
__global__ __launch_bounds__(512, 1) void rnn_pers(Params P) {
  __shared__ __align__(16) char smem[88576];
  _Float16* WH16 = (_Float16*)smem;            // mains: 333 chunks x 64 f16; aux: gmm 150 chunks
  const uint4* W4 = (const uint4*)smem;
  float* scrF = (float*)(smem + 42624);        // [8][64][8] f32
  unsigned* WAPH = (unsigned*)(smem + 59008);  // aux: Watt f16 pairs [30][200]
  float* M    = (float*)(smem + 83008);
  float* bcl  = M;                 // 24
  float* bgl  = M + 24;            // 8
  float* parts= M + 32;            // 240
  float* abk  = M + 272;           // 30
  float* kapl = M + 302;           // 20 (2 local batches)
  float* phi  = M + 322;           // 50
  float* winl = M + 372;           // 80
  float* batl = M + 452;           // 30
  float* rawl = M + 482;           // 121
  float* smx  = M + 603;           // 2
  unsigned* h1p = (unsigned*)(M + 605); // 200
  int*   csl  = (int*)(M + 805);   // 100
  int*   cll  = (int*)(M + 905);   // 2

  const int w = blockIdx.x, tid = threadIdx.x;
  const int ks = tid >> 6, b = tid & 63;
  int rlo = 0, nr = 0, blo = 0, bhi = 0;

  // ---- one-time staging ----
  if (w < NMAIN) {
    for (int slot = 0; slot < 8; ++slot) {
      const int dd = slot >> 2, g = slot & 3, gr = g*400 + 2*w + dd;
      const float* ih1 = P.Wih1 + (size_t)gr*80;
      const float* hh1 = P.Whh1 + (size_t)gr*400;
      for (int k = tid; k < 488; k += 512) {
        float v;
        if (k < 80)       v = (k < 77) ? ih1[k] : 0.f;
        else if (k < 88)  v = (k - 80 < 3) ? ih1[77 + (k - 80)] : 0.f;
        else              v = hh1[k - 88];
        WH16[(0 + (k>>3))*64 + slot*8 + (k&7)] = (_Float16)v;
      }
      const float* ih2 = P.Wih2 + (size_t)gr*480;
      const float* hh2 = P.Whh2 + (size_t)gr*400;
      for (int k = tid; k < 888; k += 512) {
        float v;
        if (k < 8)        v = (k < 3) ? ih2[k] : 0.f;
        else if (k < 408) v = ih2[3 + (k - 8)];
        else if (k < 808) v = hh2[k - 408];
        else              v = (k - 808 < 77) ? ih2[403 + (k - 808)] : 0.f;
        WH16[(61 + (k>>3))*64 + slot*8 + (k&7)] = (_Float16)v;
      }
      const float* ih3 = P.Wih3 + (size_t)gr*880;
      const float* hh3 = P.Whh3 + (size_t)gr*400;
      for (int k = tid; k < 1288; k += 512) {
        float v;
        if (k < 8)         v = (k < 3) ? ih3[k] : 0.f;
        else if (k < 408)  v = ih3[3 + (k - 8)];
        else if (k < 808)  v = hh3[k - 408];
        else if (k < 1208) v = ih3[403 + (k - 808)];
        else               v = (k - 1208 < 77) ? ih3[803 + (k - 1208)] : 0.f;
        WH16[(172 + (k>>3))*64 + slot*8 + (k&7)] = (_Float16)v;
      }
    }
    if (tid < 24) {
      int L = tid >> 3, slot = tid & 7, dd = slot >> 2, g = slot & 3;
      bcl[tid] = P.BC[L*1600 + g*400 + 2*w + dd];
    }
  } else {
    const int q = w - NMAIN;
    rlo = (121*q)/NAUX;
    nr  = (121*(q+1))/NAUX - rlo;
    blo = (64*q)/NAUX;
    bhi = (64*(q+1))/NAUX;
    for (int j = 0; j < 8; ++j)
      for (int k = tid; k < 1200; k += 512)
        WH16[(k>>3)*64 + j*8 + (k&7)] = (_Float16)((j < nr) ? P.Wgmm[(size_t)(rlo + j)*1200 + k] : 0.f);
    if (tid < 8) bgl[tid] = (tid < nr) ? P.bgmm[rlo + tid] : 0.f;
    for (int i = tid; i < 6000; i += 512) {
      int j = i / 200, pr = i % 200;
      h2v pk = { (_Float16)P.Watt[j*400 + 2*pr], (_Float16)P.Watt[j*400 + 2*pr + 1] };
      WAPH[i] = __builtin_bit_cast(unsigned, pk);
    }
    if (tid < 30) batl[tid] = P.batt[tid];
    for (int lb = 0; lb < bhi - blo; ++lb) {
      if (tid < 50) csl[lb*50 + tid] = P.cs[(blo + lb)*50 + tid];
      if (tid == 0) cll[lb] = P.cl[blo + lb];
    }
    if (tid < 20) kapl[tid] = 0.f;
  }
  __syncthreads();

  int ph = 0;
  float c1 = 0.f, c2 = 0.f, c3 = 0.f;
  float ac2[8], ac3[8];
  for (int t = 0; t <= NT; ++t) {
    const int cu = t & 1, pv = (t + 1) & 1;
    // ---- P1: L1(t) on mains || GMM(t-1) on aux ----
    if (w < NMAIN) {
      if (t < NT) {
        float ac1[8] = {0.f,0.f,0.f,0.f,0.f,0.f,0.f,0.f};
        lacc_seg(ac1, W4, 0,  P.WINH + (size_t)pv*5120, 10, 80, b, ks);
        lacc_seg(ac1, W4, 10, P.XTH + (size_t)t*512, 1, 8, b, ks);
        lacc_seg(ac1, W4, 11, P.H1H + (size_t)pv*25600, 50, 400, b, ks);
        lfinish(ac1, scrF, bcl, 0, P.H1H, cu, w, c1);
      }
    } else if (t >= 1) gmm_do(P, W4, scrF, bgl, rlo, nr, t - 1);
    tbar(P.CNT, w, ph);
    // ---- P2: L2-partial on mains || att(t)+yepi(t-1) on aux ----
    if (w < NMAIN) {
      if (t < NT) {
#pragma unroll
        for (int j = 0; j < 8; ++j) ac2[j] = 0.f;
        lacc_seg(ac2, W4, 61,  P.XTH + (size_t)t*512, 1, 8, b, ks);
        lacc_seg(ac2, W4, 62,  P.H1H + (size_t)cu*25600, 50, 400, b, ks);
        lacc_seg(ac2, W4, 112, P.H2H + (size_t)pv*25600, 50, 400, b, ks);
      }
    } else {
      if (t < NT)
        for (int lb = 0; lb < bhi - blo; ++lb)
          att_do(P, WAPH, h1p, parts, abk, kapl, phi, winl, batl, csl, cll, blo + lb, lb, t);
      if (t >= 1)
        for (int lb = 0; lb < bhi - blo; ++lb)
          yepi_do(P, rawl, smx, blo + lb, t - 1);
    }
    tbar(P.CNT, w, ph);
    if (t == NT) break;
    // ---- P3: L2-finish + L3-partial on mains ----
    if (w < NMAIN) {
      lacc_seg(ac2, W4, 162, P.WINH + (size_t)cu*5120, 10, 80, b, ks);
      lfinish(ac2, scrF, bcl, 1, P.H2H, cu, w, c2);
#pragma unroll
      for (int j = 0; j < 8; ++j) ac3[j] = 0.f;
      lacc_seg(ac3, W4, 172, P.XTH + (size_t)t*512, 1, 8, b, ks);
      lacc_seg(ac3, W4, 173, P.H1H + (size_t)cu*25600, 50, 400, b, ks);
      lacc_seg(ac3, W4, 223, P.H3H + (size_t)pv*25600, 50, 400, b, ks);
    }
    tbar(P.CNT, w, ph);
    // ---- P4: L3-finish on mains ----
    if (w < NMAIN) {
      lacc_seg(ac3, W4, 273, P.H2H + (size_t)cu*25600, 50, 400, b, ks);
      lacc_seg(ac3, W4, 323, P.WINH + (size_t)cu*5120, 10, 80, b, ks);
      lfinish(ac3, scrF, bcl, 2, P.H3H, cu, w, c3);
    }
    tbar(P.CNT, w, ph);
  }
}

extern "C" void kernel_launch(void* const* d_in, const int* in_sizes, int n_in,
                              void* d_out, int out_size, void* d_ws, size_t ws_size,
                              hipStream_t stream) {
  (void)in_sizes; (void)n_in; (void)out_size; (void)ws_size;
  Params P;
  P.x    = (const float*)d_in[0];
  P.cs   = (const int*)d_in[1];
  P.cl   = (const int*)d_in[2];
  P.bias = (const float*)d_in[3];
  P.Wih1 = (const float*)d_in[4];  P.Whh1 = (const float*)d_in[5];
  P.bih1 = (const float*)d_in[6];  P.bhh1 = (const float*)d_in[7];
  P.Wih2 = (const float*)d_in[8];  P.Whh2 = (const float*)d_in[9];
  P.bih2 = (const float*)d_in[10]; P.bhh2 = (const float*)d_in[11];
  P.Wih3 = (const float*)d_in[12]; P.Whh3 = (const float*)d_in[13];
  P.bih3 = (const float*)d_in[14]; P.bhh3 = (const float*)d_in[15];
  P.Watt = (const float*)d_in[16]; P.batt = (const float*)d_in[17];
  P.Wgmm = (const float*)d_in[18]; P.bgmm = (const float*)d_in[19];
  char* ws = (char*)d_ws;
  P.XTH  = (_Float16*)(ws + OFF_XTH);
  P.H1H  = (_Float16*)(ws + OFF_H1H);
  P.H2H  = (_Float16*)(ws + OFF_H2H);
  P.H3H  = (_Float16*)(ws + OFF_H3H);
  P.WINH = (_Float16*)(ws + OFF_WINH);
  P.BC   = (float*)(ws + OFF_BC);
  P.GY   = (float*)(ws + OFF_GY);
  P.CNT  = (int*)(ws + OFF_CNT);
  P.out  = (float*)d_out;

  hipLaunchKernelGGL(prep_k, dim3(1024), dim3(256), 0, stream, P);
  hipLaunchKernelGGL(rnn_pers, dim3(256), dim3(512), 0, stream, P);
}

// Round 9
// 31648.236 us; speedup vs baseline: 8.1793x; 1.0667x over previous
//
#include <hip/hip_runtime.h>
#include <stdint.h>

#define NT 600
#define NMAIN 200
#define NWG 256

// ---- ws layout (bytes) ----
#define OFF_XTH  0          // [600][64][8]   f16  614400
#define OFF_H1H  614400     // [4][64][448]   f16  229376
#define OFF_H2H  843776     // [2][64][448]   f16  114688
#define OFF_H3H  958464     // [2][64][448]   f16  114688
#define OFF_WINH 1073152    // [2][64][128]   f16  32768
#define OFF_BC   1105920    // [3][1600]      f32  19200
#define OFF_GY   1125120    // [64][128]      f32  32768
#define OFF_CNT  1157888    // [16*32]        i32  2048

#define HROW 448
#define HSLOT 28672   // 64*448
#define WROW 128
#define WSLOT 8192    // 64*128

// weight chunk map (chunk = 8 k x 8 slots x f16 = 128B)
// L1: win[0,16) x{16} h1[17,73)
// L2: x{73} h1[74,130) h2p[130,186) win[186,202)
// L3: x{202} h1[203,259) h3p[259,315) h2c[315,371) win[371,387)
// GMM(aux): h1[0,56) h2[56,112) h3[112,168)

typedef _Float16 h2v __attribute__((ext_vector_type(2)));

struct Params {
  const float* x; const int* cs; const int* cl; const float* bias;
  const float *Wih1,*Whh1,*bih1,*bhh1,*Wih2,*Whh2,*bih2,*bhh2,*Wih3,*Whh3,*bih3,*bhh3;
  const float *Watt,*batt,*Wgmm,*bgmm;
  _Float16 *XTH,*H1H,*H2H,*H3H,*WINH;
  float *BC,*GY;
  int *CNT;
  float* out;
};

__device__ __forceinline__ float sigm(float x) { return 1.f / (1.f + expf(-x)); }

__device__ __forceinline__ float FDOT2(unsigned a, unsigned b, float c) {
#if __has_builtin(__builtin_amdgcn_fdot2)
  return __builtin_amdgcn_fdot2(__builtin_bit_cast(h2v, a), __builtin_bit_cast(h2v, b), c, false);
#else
  h2v x = __builtin_bit_cast(h2v, a), y = __builtin_bit_cast(h2v, b);
  return c + (float)x[0]*(float)y[0] + (float)x[1]*(float)y[1];
#endif
}

__device__ __forceinline__ void tbar(int* C, int w, int& ph) {
  __syncthreads();
  if (threadIdx.x == 0)
    __hip_atomic_fetch_add(&C[(w & 15)*32], 1, __ATOMIC_RELEASE, __HIP_MEMORY_SCOPE_AGENT);
  ++ph;
  const int tgt = 16*ph;
  if (threadIdx.x < 16) {
    while (__hip_atomic_load(&C[threadIdx.x*32], __ATOMIC_RELAXED, __HIP_MEMORY_SCOPE_AGENT) < tgt)
      __builtin_amdgcn_s_sleep(1);
    (void)__hip_atomic_load(&C[threadIdx.x*32], __ATOMIC_ACQUIRE, __HIP_MEMORY_SCOPE_AGENT);
  }
  __syncthreads();
}

// =====================  prep  =====================
__global__ void prep_k(Params P) {
  const long long NX  = 600LL*512;
  const long long NH1 = 4LL*64*448;
  const long long NH2 = 2LL*64*448;
  const long long NWH = 2LL*64*128;
  const long long NBc = 4800;
  const long long NCt = 512;
  const long long TOT = NX + NH1 + 2*NH2 + NWH + NBc + NCt;
  const long long stride = (long long)gridDim.x * blockDim.x;
  for (long long idx = (long long)blockIdx.x*blockDim.x + threadIdx.x; idx < TOT; idx += stride) {
    long long i = idx;
    if (i < NX) {
      int t = (int)(i >> 9);
      int rem = (int)(i & 511);
      int b = rem >> 3, k = rem & 7;
      float v = (k < 3) ? P.x[((size_t)b*NT + t)*3 + k] : 0.f;
      P.XTH[i] = (_Float16)v;
      continue;
    }
    i -= NX;
    if (i < NH1) { P.H1H[i] = (_Float16)0.f; continue; } i -= NH1;
    if (i < NH2) { P.H2H[i] = (_Float16)0.f; continue; } i -= NH2;
    if (i < NH2) { P.H3H[i] = (_Float16)0.f; continue; } i -= NH2;
    if (i < NWH) { P.WINH[i] = (_Float16)0.f; continue; } i -= NWH;
    if (i < NBc) {
      int l = (int)(i / 1600), r = (int)(i % 1600);
      const float* bi = (l==0)?P.bih1:(l==1)?P.bih2:P.bih3;
      const float* bh = (l==0)?P.bhh1:(l==1)?P.bhh2:P.bhh3;
      P.BC[i] = bi[r] + bh[r];
      continue;
    }
    i -= NBc;
    P.CNT[i] = 0;
  }
}

__device__ __forceinline__ void comp_chunk(float (&ac)[8], const uint4* W4, int wc, uint4 sv) {
  const uint4* p = W4 + (size_t)wc*8;
#pragma unroll
  for (int j = 0; j < 8; ++j) {
    uint4 wv = p[j];
    float a = ac[j];
    a = FDOT2(sv.x, wv.x, a);
    a = FDOT2(sv.y, wv.y, a);
    a = FDOT2(sv.z, wv.z, a);
    a = FDOT2(sv.w, wv.w, a);
    ac[j] = a;
  }
}

// reduce 8-wave partials, LSTM nonlinearity, packed u32 h-write (verified round-8 math)
__device__ __forceinline__ void lfinish(float (&ac)[8], float* scrF, const float* bcl,
    int Lidx, _Float16* HSLOTP, int w, float& cref) {
  const int tid = threadIdx.x, ks = tid >> 6, b = tid & 63;
  __syncthreads();   // protect scrF reuse
#pragma unroll
  for (int j = 0; j < 8; ++j) scrF[(ks*64 + b)*8 + j] = ac[j];
  __syncthreads();
  const int r = tid & 7;
  float D = 0.f;
#pragma unroll
  for (int k = 0; k < 8; ++k) D += scrF[k*512 + tid];
  D += bcl[Lidx*8 + r];
  float v1 = __shfl_xor(D, 1);
  float v2 = __shfl_xor(D, 2);
  float v3 = __shfl_xor(D, 3);
  if ((tid & 3) == 0) {   // r in {0,4}: gates (i,f,g,o) = (D,v1,v2,v3)
    float c = sigm(v1)*cref + sigm(D)*tanhf(v2);
    cref = c;
    float h = sigm(v3)*tanhf(c);
    unsigned hu = (unsigned)__builtin_bit_cast(unsigned short, (_Float16)h);
    unsigned other = (unsigned)__shfl_xor((int)hu, 4);
    if (r == 0) {
      const int b2 = tid >> 3;
      *(unsigned*)(HSLOTP + (size_t)b2*HROW + 2*w) = hu | (other << 16);
    }
  }
}

// GMM rows rlo..rlo+nr-1 for step tt -> GY[b][r]
__device__ __forceinline__ void gmm_do(const Params& P, const uint4* W4, float* scrF,
                                       const float* bgl, int rlo, int nr, int tt) {
  const int tid = threadIdx.x, ks = tid >> 6, b = tid & 63;
  const int s1 = tt & 3, s23 = tt & 1;
  const _Float16* h1 = P.H1H + (size_t)s1*HSLOT + (size_t)b*HROW;
  const _Float16* h2 = P.H2H + (size_t)s23*HSLOT + (size_t)b*HROW;
  const _Float16* h3 = P.H3H + (size_t)s23*HSLOT + (size_t)b*HROW;
  uint4 v1[7], v2[7], v3[7];
#pragma unroll
  for (int i = 0; i < 7; ++i) v1[i] = *(const uint4*)(h1 + (ks + 8*i)*8);
#pragma unroll
  for (int i = 0; i < 7; ++i) v2[i] = *(const uint4*)(h2 + (ks + 8*i)*8);
#pragma unroll
  for (int i = 0; i < 7; ++i) v3[i] = *(const uint4*)(h3 + (ks + 8*i)*8);
  float ac[8] = {0.f,0.f,0.f,0.f,0.f,0.f,0.f,0.f};
#pragma unroll
  for (int i = 0; i < 7; ++i) comp_chunk(ac, W4, 0 + ks + 8*i, v1[i]);
#pragma unroll
  for (int i = 0; i < 7; ++i) comp_chunk(ac, W4, 56 + ks + 8*i, v2[i]);
#pragma unroll
  for (int i = 0; i < 7; ++i) comp_chunk(ac, W4, 112 + ks + 8*i, v3[i]);
  __syncthreads();
#pragma unroll
  for (int j = 0; j < 8; ++j) scrF[(ks*64 + b)*8 + j] = ac[j];
  __syncthreads();
  const int r = tid & 7, b2 = tid >> 3;
  float D = 0.f;
#pragma unroll
  for (int k = 0; k < 8; ++k) D += scrF[k*512 + tid];
  if (r < nr) P.GY[b2*128 + rlo + r] = D + bgl[r];
}

// attention window for batch b (local slot lb); verified round-8 math (+parallel scatter)
__device__ __forceinline__ void att_do(const Params& P, const unsigned* WAPH, unsigned* h1p,
    float* parts, float* abk, float* kapl, float* phi, float* winl,
    const float* batl, const int* csl, const int* cll, int b, int lb, int t) {
  const int tid = threadIdx.x;
  const int s1 = t & 3, sw = t & 1;
  if (tid < 224) h1p[tid] = ((const unsigned*)(P.H1H + (size_t)s1*HSLOT + (size_t)b*HROW))[tid];
  __syncthreads();
  if (tid < 240) {
    int j = tid >> 3, pp = tid & 7;
    const unsigned* wr = WAPH + j*200 + pp*25;
    const unsigned* hr = h1p + pp*25;
    float acc = 0.f;
#pragma unroll
    for (int m = 0; m < 25; ++m) acc = FDOT2(hr[m], wr[m], acc);
    parts[tid] = acc;
  }
  __syncthreads();
  if (tid < 30) {
    float s = batl[tid];
#pragma unroll
    for (int pp = 0; pp < 8; ++pp) s += parts[tid*8 + pp];
    abk[tid] = expf(s);
  }
  __syncthreads();
  if (tid < 10) kapl[lb*10 + tid] += abk[20 + tid];
  __syncthreads();
  if (tid < 50) {
    float s = 0.f;
    if (tid < cll[lb]) {
#pragma unroll
      for (int k = 0; k < 10; ++k) {
        float dk = kapl[lb*10 + k] - (float)tid;
        s += abk[k]*expf(-abk[10 + k]*dk*dk);
      }
    }
    phi[tid] = s;
  }
  __syncthreads();
  if (tid < 77) {               // parallel gather: deterministic
    float s = 0.f;
    for (int u = 0; u < 50; ++u) s += (csl[lb*50 + u] == tid) ? phi[u] : 0.f;
    winl[tid] = s;
  }
  __syncthreads();
  if (tid < 64) {
    int a0 = 2*tid, a1 = 2*tid + 1;
    h2v pk = { (_Float16)((a0 < 77) ? winl[a0] : 0.f),
               (_Float16)((a1 < 77) ? winl[a1] : 0.f) };
    *(unsigned*)(P.WINH + (size_t)sw*WSLOT + (size_t)b*WROW + a0) =
        __builtin_bit_cast(unsigned, pk);
  }
  __syncthreads();
}

// y epilogue for batch b, step tt (verified round-8 math)
__device__ __forceinline__ void yepi_do(const Params& P, float* rawl, float* smx, int b, int tt) {
  const int tid = threadIdx.x;
  __syncthreads();
  if (tid < 121) rawl[tid] = P.GY[b*128 + tid];
  __syncthreads();
  const float bia = P.bias[b];
  if (tid == 0) {
    float m = -1e30f;
    for (int j = 1; j <= 20; ++j) m = fmaxf(m, rawl[j]*(1.f + bia));
    float ss = 0.f;
    for (int j = 1; j <= 20; ++j) ss += expf(rawl[j]*(1.f + bia) - m);
    smx[0] = m; smx[1] = ss;
  }
  __syncthreads();
  float* yr = P.out + ((size_t)b*NT + tt)*121;
  if (tid == 0)           yr[120] = 1.f/(1.f + expf(-rawl[0]));
  else if (tid <= 20)     yr[tid - 1] = expf(rawl[tid]*(1.f + bia) - smx[0]) / smx[1];
  else if (tid <= 60)     yr[80 + tid - 21] = rawl[tid];
  else if (tid <= 100)    yr[20 + tid - 61] = expf(rawl[tid] - bia);
  else if (tid <= 120)    yr[60 + tid - 101] = tanhf(rawl[tid]);
  __syncthreads();
}

// =====================  persistent kernel: 256 WGs x 512 threads, 2-barrier pipeline =====================
__global__ __launch_bounds__(512, 1) void rnn_pers(Params P) {
  __shared__ __align__(16) char smem[69888];
  _Float16* WH16 = (_Float16*)smem;            // mains: 387 chunks; aux: gmm 168 chunks
  const uint4* W4 = (const uint4*)smem;
  unsigned* WAPH = (unsigned*)(smem + 21504);  // aux only: Watt f16 pairs [30][200] (24000 B)
  float* scrF = (float*)(smem + 49536);        // [8][64][8] f32 (16384 B)
  float* M    = (float*)(smem + 65920);
  float* bcl  = M;                 // 24
  float* bgl  = M + 24;            // 8
  float* parts= M + 32;            // 240
  float* abk  = M + 272;           // 30
  float* kapl = M + 302;           // 20
  float* phi  = M + 322;           // 50
  float* winl = M + 372;           // 80
  float* batl = M + 452;           // 30
  float* rawl = M + 482;           // 121
  float* smx  = M + 603;           // 2
  unsigned* h1p = (unsigned*)(M + 605); // 224
  int*   csl  = (int*)(M + 829);   // 100
  int*   cll  = (int*)(M + 929);   // 2

  const int w = blockIdx.x, tid = threadIdx.x;
  const int ks = tid >> 6, b = tid & 63;
  int rlo = 0, nr = 0, blo = 0, bhi = 0;

  // ---- one-time staging ----
  if (w < NMAIN) {
    for (int slot = 0; slot < 8; ++slot) {
      const int dd = slot >> 2, g = slot & 3, gr = g*400 + 2*w + dd;
      const float* ih1 = P.Wih1 + (size_t)gr*80;
      const float* hh1 = P.Whh1 + (size_t)gr*400;
      const float* ih2 = P.Wih2 + (size_t)gr*480;
      const float* hh2 = P.Whh2 + (size_t)gr*400;
      const float* ih3 = P.Wih3 + (size_t)gr*880;
      const float* hh3 = P.Whh3 + (size_t)gr*400;
      for (int k = tid; k < 128; k += 512)
        WH16[(0 + (k>>3))*64 + slot*8 + (k&7)] = (_Float16)((k < 77) ? ih1[k] : 0.f);
      for (int k = tid; k < 8; k += 512)
        WH16[16*64 + slot*8 + k] = (_Float16)((k < 3) ? ih1[77 + k]*0.125f : 0.f);
      for (int k = tid; k < 448; k += 512)
        WH16[(17 + (k>>3))*64 + slot*8 + (k&7)] = (_Float16)((k < 400) ? hh1[k] : 0.f);
      for (int k = tid; k < 8; k += 512)
        WH16[73*64 + slot*8 + k] = (_Float16)((k < 3) ? ih2[k]*0.125f : 0.f);
      for (int k = tid; k < 448; k += 512)
        WH16[(74 + (k>>3))*64 + slot*8 + (k&7)] = (_Float16)((k < 400) ? ih2[3 + k] : 0.f);
      for (int k = tid; k < 448; k += 512)
        WH16[(130 + (k>>3))*64 + slot*8 + (k&7)] = (_Float16)((k < 400) ? hh2[k] : 0.f);
      for (int k = tid; k < 128; k += 512)
        WH16[(186 + (k>>3))*64 + slot*8 + (k&7)] = (_Float16)((k < 77) ? ih2[403 + k] : 0.f);
      for (int k = tid; k < 8; k += 512)
        WH16[202*64 + slot*8 + k] = (_Float16)((k < 3) ? ih3[k]*0.125f : 0.f);
      for (int k = tid; k < 448; k += 512)
        WH16[(203 + (k>>3))*64 + slot*8 + (k&7)] = (_Float16)((k < 400) ? ih3[3 + k] : 0.f);
      for (int k = tid; k < 448; k += 512)
        WH16[(259 + (k>>3))*64 + slot*8 + (k&7)] = (_Float16)((k < 400) ? hh3[k] : 0.f);
      for (int k = tid; k < 448; k += 512)
        WH16[(315 + (k>>3))*64 + slot*8 + (k&7)] = (_Float16)((k < 400) ? ih3[403 + k] : 0.f);
      for (int k = tid; k < 128; k += 512)
        WH16[(371 + (k>>3))*64 + slot*8 + (k&7)] = (_Float16)((k < 77) ? ih3[803 + k] : 0.f);
    }
    if (tid < 24) {
      int L = tid >> 3, slot = tid & 7, dd = slot >> 2, g = slot & 3;
      bcl[tid] = P.BC[L*1600 + g*400 + 2*w + dd];
    }
  } else {
    const int q = w - NMAIN, NAUX = NWG - NMAIN;
    rlo = (121*q)/NAUX;
    nr  = (121*(q+1))/NAUX - rlo;
    blo = (64*q)/NAUX;
    bhi = (64*(q+1))/NAUX;
    for (int j = 0; j < 8; ++j) {
      for (int k = tid; k < 448; k += 512) {
        float a = (j < nr && k < 400) ? P.Wgmm[(size_t)(rlo + j)*1200 + k] : 0.f;
        float bv = (j < nr && k < 400) ? P.Wgmm[(size_t)(rlo + j)*1200 + 400 + k] : 0.f;
        float cv = (j < nr && k < 400) ? P.Wgmm[(size_t)(rlo + j)*1200 + 800 + k] : 0.f;
        WH16[(0 + (k>>3))*64 + j*8 + (k&7)]   = (_Float16)a;
        WH16[(56 + (k>>3))*64 + j*8 + (k&7)]  = (_Float16)bv;
        WH16[(112 + (k>>3))*64 + j*8 + (k&7)] = (_Float16)cv;
      }
    }
    if (tid < 8) bgl[tid] = (tid < nr) ? P.bgmm[rlo + tid] : 0.f;
    for (int i = tid; i < 6000; i += 512) {
      int j = i / 200, pr = i % 200;
      h2v pk = { (_Float16)P.Watt[j*400 + 2*pr], (_Float16)P.Watt[j*400 + 2*pr + 1] };
      WAPH[i] = __builtin_bit_cast(unsigned, pk);
    }
    if (tid < 30) batl[tid] = P.batt[tid];
    for (int lb = 0; lb < bhi - blo; ++lb) {
      if (tid < 50) csl[lb*50 + tid] = P.cs[(blo + lb)*50 + tid];
      if (tid == 0) cll[lb] = P.cl[blo + lb];
    }
    if (tid < 20) kapl[tid] = 0.f;
  }
  __syncthreads();

  int ph = 0;
  float c1 = 0.f, c2 = 0.f, c3 = 0.f;
  for (int t = 0; t <= NT + 1; ++t) {
    const bool doL1 = (t < NT), doL2 = (t >= 1 && t <= NT), doAux = (t >= 2);
    // ======== Phase A: L1(t) + L2(t-1) on mains || GMM(t-2) on aux ========
    if (w < NMAIN) {
      const int s1r = (t + 3) & 3;             // h1[(t-1)&3]
      const int pw  = (t + 1) & 1;             // win[(t-1)&1]
      uint4 vw0, vw1, vx, vxm, vh[7], vh2[7];
      if (doL1 || doL2) {
        const _Float16* win = P.WINH + (size_t)pw*WSLOT + (size_t)b*WROW;
        vw0 = *(const uint4*)(win + ks*8);
        vw1 = *(const uint4*)(win + (ks + 8)*8);
        const _Float16* h1 = P.H1H + (size_t)s1r*HSLOT + (size_t)b*HROW;
#pragma unroll
        for (int i = 0; i < 7; ++i) vh[i] = *(const uint4*)(h1 + (ks + 8*i)*8);
      }
      if (doL1) vx = *(const uint4*)(P.XTH + (size_t)t*512 + b*8);
      if (doL2) {
        vxm = *(const uint4*)(P.XTH + (size_t)(t - 1)*512 + b*8);
        const _Float16* h2p = P.H2H + (size_t)(t & 1)*HSLOT + (size_t)b*HROW; // h2[(t-2)&1]
#pragma unroll
        for (int i = 0; i < 7; ++i) vh2[i] = *(const uint4*)(h2p + (ks + 8*i)*8);
      }
      if (doL1) {
        float ac[8] = {0.f,0.f,0.f,0.f,0.f,0.f,0.f,0.f};
        comp_chunk(ac, W4, 0 + ks, vw0);
        comp_chunk(ac, W4, 0 + ks + 8, vw1);
        comp_chunk(ac, W4, 16, vx);
#pragma unroll
        for (int i = 0; i < 7; ++i) comp_chunk(ac, W4, 17 + ks + 8*i, vh[i]);
        lfinish(ac, scrF, bcl, 0, P.H1H + (size_t)(t & 3)*HSLOT, w, c1);
      }
      if (doL2) {
        float ac[8] = {0.f,0.f,0.f,0.f,0.f,0.f,0.f,0.f};
        comp_chunk(ac, W4, 73, vxm);
#pragma unroll
        for (int i = 0; i < 7; ++i) comp_chunk(ac, W4, 74 + ks + 8*i, vh[i]);
#pragma unroll
        for (int i = 0; i < 7; ++i) comp_chunk(ac, W4, 130 + ks + 8*i, vh2[i]);
        comp_chunk(ac, W4, 186 + ks, vw0);
        comp_chunk(ac, W4, 186 + ks + 8, vw1);
        lfinish(ac, scrF, bcl, 1, P.H2H + (size_t)((t + 1) & 1)*HSLOT, w, c2);
      }
    } else {
      if (doAux) gmm_do(P, W4, scrF, bgl, rlo, nr, t - 2);
    }
    tbar(P.CNT, w, ph);
    // ======== Phase B: L3(t-1) on mains || att(t) + yepi(t-2) on aux ========
    if (w < NMAIN) {
      if (doL2) {
        const int tm = t - 1;
        const _Float16* h1 = P.H1H + (size_t)(tm & 3)*HSLOT + (size_t)b*HROW;
        const _Float16* h3p = P.H3H + (size_t)((tm + 1) & 1)*HSLOT + (size_t)b*HROW;
        const _Float16* h2c = P.H2H + (size_t)(tm & 1)*HSLOT + (size_t)b*HROW;
        const _Float16* win = P.WINH + (size_t)(tm & 1)*WSLOT + (size_t)b*WROW;
        uint4 vx = *(const uint4*)(P.XTH + (size_t)tm*512 + b*8);
        uint4 a1[7], a3[7], a2[7], aw[2];
#pragma unroll
        for (int i = 0; i < 7; ++i) a1[i] = *(const uint4*)(h1 + (ks + 8*i)*8);
#pragma unroll
        for (int i = 0; i < 7; ++i) a3[i] = *(const uint4*)(h3p + (ks + 8*i)*8);
#pragma unroll
        for (int i = 0; i < 7; ++i) a2[i] = *(const uint4*)(h2c + (ks + 8*i)*8);
        aw[0] = *(const uint4*)(win + ks*8);
        aw[1] = *(const uint4*)(win + (ks + 8)*8);
        float ac[8] = {0.f,0.f,0.f,0.f,0.f,0.f,0.f,0.f};
        comp_chunk(ac, W4, 202, vx);
#pragma unroll
        for (int i = 0; i < 7; ++i) comp_chunk(ac, W4, 203 + ks + 8*i, a1[i]);
#pragma unroll
        for (int i = 0; i < 7; ++i) comp_chunk(ac, W4, 259 + ks + 8*i, a3[i]);
#pragma unroll
        for (int i = 0; i < 7; ++i) comp_chunk(ac, W4, 315 + ks + 8*i, a2[i]);
        comp_chunk(ac, W4, 371 + ks, aw[0]);
        comp_chunk(ac, W4, 371 + ks + 8, aw[1]);
        lfinish(ac, scrF, bcl, 2, P.H3H + (size_t)(tm & 1)*HSLOT, w, c3);
      }
    } else {
      if (doL1)
        for (int lb = 0; lb < bhi - blo; ++lb)
          att_do(P, WAPH, h1p, parts, abk, kapl, phi, winl, batl, csl, cll, blo + lb, lb, t);
      if (doAux)
        for (int lb = 0; lb < bhi - blo; ++lb)
          yepi_do(P, rawl, smx, blo + lb, t - 2);
    }
    tbar(P.CNT, w, ph);
  }
}

extern "C" void kernel_launch(void* const* d_in, const int* in_sizes, int n_in,
                              void* d_out, int out_size, void* d_ws, size_t ws_size,
                              hipStream_t stream) {
  (void)in_sizes; (void)n_in; (void)out_size; (void)ws_size;
  Params P;
  P.x    = (const float*)d_in[0];
  P.cs   = (const int*)d_in[1];
  P.cl   = (const int*)d_in[2];
  P.bias = (const float*)d_in[3];
  P.Wih1 = (const float*)d_in[4];  P.Whh1 = (const float*)d_in[5];
  P.bih1 = (const float*)d_in[6];  P.bhh1 = (const float*)d_in[7];
  P.Wih2 = (const float*)d_in[8];  P.Whh2 = (const float*)d_in[9];
  P.bih2 = (const float*)d_in[10]; P.bhh2 = (const float*)d_in[11];
  P.Wih3 = (const float*)d_in[12]; P.Whh3 = (const float*)d_in[13];
  P.bih3 = (const float*)d_in[14]; P.bhh3 = (const float*)d_in[15];
  P.Watt = (const float*)d_in[16]; P.batt = (const float*)d_in[17];
  P.Wgmm = (const float*)d_in[18]; P.bgmm = (const float*)d_in[19];
  char* ws = (char*)d_ws;
  P.XTH  = (_Float16*)(ws + OFF_XTH);
  P.H1H  = (_Float16*)(ws + OFF_H1H);
  P.H2H  = (_Float16*)(ws + OFF_H2H);
  P.H3H  = (_Float16*)(ws + OFF_H3H);
  P.WINH = (_Float16*)(ws + OFF_WINH);
  P.BC   = (float*)(ws + OFF_BC);
  P.GY   = (float*)(ws + OFF_GY);
  P.CNT  = (int*)(ws + OFF_CNT);
  P.out  = (float*)d_out;

  hipLaunchKernelGGL(prep_k, dim3(1024), dim3(256), 0, stream, P);
  hipLaunchKernelGGL(rnn_pers, dim3(NWG), dim3(512), 0, stream, P);
}

// Round 10
// 19336.255 us; speedup vs baseline: 13.3873x; 1.6367x over previous
//
#include <hip/hip_runtime.h>
#include <stdint.h>

#define NT 600
#define NMAIN 100
#define NWG 156
#define NAUX (NWG - NMAIN)

// ---- ws layout (bytes) ----
#define OFF_XTH  0          // [600][64][32]  f16  2457600
#define OFF_H1H  2457600    // [4][64][448]   f16  229376
#define OFF_H2H  2686976    // [2][64][448]   f16  114688
#define OFF_H3H  2801664    // [2][64][448]   f16  114688
#define OFF_WINH 2916352    // [2][64][128]   f16  32768
#define OFF_BC   2949120    // [3][1600]      f32  19200
#define OFF_GY   2968320    // [64][128]      f32  32768
#define OFF_CNT  3001088    // [12*32]        i32  2048

#define HROW 448
#define HSLOT 28672   // 64*448
#define WROW 128
#define WSLOT 8192    // 64*128
#define XROW 32

// k-block (32-k) lists per layer:
// L1: win[0,4) x{4} h1[5,19)                    = 19 blocks
// L2: x{0} h1[1,15) h2p[15,29) win[29,33)       = 33 blocks
// L3: x{0} h1[1,15) h3p[15,29) h2c[29,43) win[43,47) = 47 blocks

typedef _Float16 h2v __attribute__((ext_vector_type(2)));
typedef _Float16 f16x8 __attribute__((ext_vector_type(8)));
typedef float f32x4 __attribute__((ext_vector_type(4)));

struct Params {
  const float* x; const int* cs; const int* cl; const float* bias;
  const float *Wih1,*Whh1,*bih1,*bhh1,*Wih2,*Whh2,*bih2,*bhh2,*Wih3,*Whh3,*bih3,*bhh3;
  const float *Watt,*batt,*Wgmm,*bgmm;
  _Float16 *XTH,*H1H,*H2H,*H3H,*WINH;
  float *BC,*GY;
  int *CNT;
  float* out;
};

__device__ __forceinline__ float sigm(float x) { return 1.f / (1.f + expf(-x)); }

__device__ __forceinline__ float FDOT2(unsigned a, unsigned b, float c) {
#if __has_builtin(__builtin_amdgcn_fdot2)
  return __builtin_amdgcn_fdot2(__builtin_bit_cast(h2v, a), __builtin_bit_cast(h2v, b), c, false);
#else
  h2v x = __builtin_bit_cast(h2v, a), y = __builtin_bit_cast(h2v, b);
  return c + (float)x[0]*(float)y[0] + (float)x[1]*(float)y[1];
#endif
}

// 12-sub-counter barrier over 156 WGs (13 per sub-counter)
__device__ __forceinline__ void tbar(int* C, int w, int& ph) {
  __syncthreads();
  if (threadIdx.x == 0)
    __hip_atomic_fetch_add(&C[(w % 12)*32], 1, __ATOMIC_RELEASE, __HIP_MEMORY_SCOPE_AGENT);
  ++ph;
  const int tgt = 13*ph;
  if (threadIdx.x < 12) {
    while (__hip_atomic_load(&C[threadIdx.x*32], __ATOMIC_RELAXED, __HIP_MEMORY_SCOPE_AGENT) < tgt)
      __builtin_amdgcn_s_sleep(1);
    (void)__hip_atomic_load(&C[threadIdx.x*32], __ATOMIC_ACQUIRE, __HIP_MEMORY_SCOPE_AGENT);
  }
  __syncthreads();
}

// =====================  prep  =====================
__global__ void prep_k(Params P) {
  const long long NX  = 600LL*64*32;
  const long long NH1 = 4LL*64*448;
  const long long NH2 = 2LL*64*448;
  const long long NWH = 2LL*64*128;
  const long long NBc = 4800;
  const long long NCt = 512;
  const long long TOT = NX + NH1 + 2*NH2 + NWH + NBc + NCt;
  const long long stride = (long long)gridDim.x * blockDim.x;
  for (long long idx = (long long)blockIdx.x*blockDim.x + threadIdx.x; idx < TOT; idx += stride) {
    long long i = idx;
    if (i < NX) {
      int t = (int)(i >> 11);
      int rem = (int)(i & 2047);
      int b = rem >> 5, k = rem & 31;
      float v = (k < 3) ? P.x[((size_t)b*NT + t)*3 + k] : 0.f;
      P.XTH[i] = (_Float16)v;
      continue;
    }
    i -= NX;
    if (i < NH1) { P.H1H[i] = (_Float16)0.f; continue; } i -= NH1;
    if (i < NH2) { P.H2H[i] = (_Float16)0.f; continue; } i -= NH2;
    if (i < NH2) { P.H3H[i] = (_Float16)0.f; continue; } i -= NH2;
    if (i < NWH) { P.WINH[i] = (_Float16)0.f; continue; } i -= NWH;
    if (i < NBc) {
      int l = (int)(i / 1600), r = (int)(i % 1600);
      const float* bi = (l==0)?P.bih1:(l==1)?P.bih2:P.bih3;
      const float* bh = (l==0)?P.bhh1:(l==1)?P.bhh2:P.bhh3;
      P.BC[i] = bi[r] + bh[r];
      continue;
    }
    i -= NBc;
    P.CNT[i] = 0;
  }
}

// =====================  MFMA LSTM layer  =====================
// D[m][n]: m = gate-row (dd*4+g), n = batch. A = weights (VGPR-resident),
// B[k][n] = state[n][k] read per-lane from global.
template<int L, int NBLK, int MAXI>
__device__ __forceinline__ void mfma_layer(const Params& P, const uint4* af,
    float* scr, float* gsum, const float* bcl, int w, int tt, float& cref, _Float16* Hout) {
  const int tid = threadIdx.x, ks = tid >> 6, l = tid & 63;
  uint4 bf[MAXI][4];
#pragma unroll
  for (int i = 0; i < MAXI; ++i) {
    const int kb = ks + 8*i;
    if (kb < NBLK) {
      const _Float16* bp; int k0, st;
      if constexpr (L == 0) {
        if (kb < 4)       { bp = P.WINH + (size_t)((tt+1)&1)*WSLOT; st = WROW; k0 = kb*32; }
        else if (kb == 4) { bp = P.XTH + (size_t)tt*2048;           st = XROW; k0 = 0; }
        else              { bp = P.H1H + (size_t)((tt+3)&3)*HSLOT;  st = HROW; k0 = (kb-5)*32; }
      } else if constexpr (L == 1) {
        if (kb == 0)      { bp = P.XTH + (size_t)tt*2048;           st = XROW; k0 = 0; }
        else if (kb < 15) { bp = P.H1H + (size_t)(tt&3)*HSLOT;      st = HROW; k0 = (kb-1)*32; }
        else if (kb < 29) { bp = P.H2H + (size_t)((tt+1)&1)*HSLOT;  st = HROW; k0 = (kb-15)*32; }
        else              { bp = P.WINH + (size_t)(tt&1)*WSLOT;     st = WROW; k0 = (kb-29)*32; }
      } else {
        if (kb == 0)      { bp = P.XTH + (size_t)tt*2048;           st = XROW; k0 = 0; }
        else if (kb < 15) { bp = P.H1H + (size_t)(tt&3)*HSLOT;      st = HROW; k0 = (kb-1)*32; }
        else if (kb < 29) { bp = P.H3H + (size_t)((tt+1)&1)*HSLOT;  st = HROW; k0 = (kb-15)*32; }
        else if (kb < 43) { bp = P.H2H + (size_t)(tt&1)*HSLOT;      st = HROW; k0 = (kb-29)*32; }
        else              { bp = P.WINH + (size_t)(tt&1)*WSLOT;     st = WROW; k0 = (kb-43)*32; }
      }
      const _Float16* base = bp + (size_t)(l & 15)*st + k0 + ((l >> 4)*8);
#pragma unroll
      for (int ct = 0; ct < 4; ++ct)
        bf[i][ct] = *(const uint4*)(base + (size_t)ct*16*st);
    }
  }
  f32x4 acc[4] = {{0.f,0.f,0.f,0.f},{0.f,0.f,0.f,0.f},{0.f,0.f,0.f,0.f},{0.f,0.f,0.f,0.f}};
#pragma unroll
  for (int i = 0; i < MAXI; ++i) {
    const int kb = ks + 8*i;
    if (kb < NBLK) {
#pragma unroll
      for (int ct = 0; ct < 4; ++ct)
        acc[ct] = __builtin_amdgcn_mfma_f32_16x16x32_f16(
            __builtin_bit_cast(f16x8, af[i]), __builtin_bit_cast(f16x8, bf[i][ct]),
            acc[ct], 0, 0, 0);
    }
  }
  __syncthreads();   // protect scr reuse
#pragma unroll
  for (int ct = 0; ct < 4; ++ct)
    *(f32x4*)&scr[((size_t)(ks*64 + ct*16 + (l & 15)))*21 + (l >> 4)*4] = acc[ct];
  __syncthreads();
#pragma unroll
  for (int p = 0; p < 2; ++p) {
    const int idx = tid + p*512, m = idx >> 6, b = idx & 63;
    float s = 0.f;
#pragma unroll
    for (int k = 0; k < 8; ++k) s += scr[(size_t)(k*64 + b)*21 + m];
    gsum[b*21 + m] = s + bcl[L*16 + m];
  }
  __syncthreads();
  if (tid < 256) {
    const int dd = tid >> 6, b = tid & 63;
    const float* gp = gsum + b*21 + dd*4;
    float c = sigm(gp[1])*cref + sigm(gp[0])*tanhf(gp[2]);
    cref = c;
    float h = sigm(gp[3])*tanhf(c);
    Hout[(size_t)b*HROW + 4*w + dd] = (_Float16)h;
  }
}

// =====================  aux phases (verified round-9 code)  =====================
__device__ __forceinline__ void gmm_do(const Params& P, const uint4* W4, float* scrF,
                                       const float* bgl, int rlo, int nr, int tt) {
  const int tid = threadIdx.x, ks = tid >> 6, b = tid & 63;
  const int s1 = tt & 3, s23 = tt & 1;
  const _Float16* h1 = P.H1H + (size_t)s1*HSLOT + (size_t)b*HROW;
  const _Float16* h2 = P.H2H + (size_t)s23*HSLOT + (size_t)b*HROW;
  const _Float16* h3 = P.H3H + (size_t)s23*HSLOT + (size_t)b*HROW;
  uint4 v1[7], v2[7], v3[7];
#pragma unroll
  for (int i = 0; i < 7; ++i) v1[i] = *(const uint4*)(h1 + (ks + 8*i)*8);
#pragma unroll
  for (int i = 0; i < 7; ++i) v2[i] = *(const uint4*)(h2 + (ks + 8*i)*8);
#pragma unroll
  for (int i = 0; i < 7; ++i) v3[i] = *(const uint4*)(h3 + (ks + 8*i)*8);
  float ac[8] = {0.f,0.f,0.f,0.f,0.f,0.f,0.f,0.f};
  auto comp = [&](int wc, uint4 sv) {
    const uint4* p = W4 + (size_t)wc*8;
#pragma unroll
    for (int j = 0; j < 8; ++j) {
      uint4 wv = p[j];
      float a = ac[j];
      a = FDOT2(sv.x, wv.x, a);
      a = FDOT2(sv.y, wv.y, a);
      a = FDOT2(sv.z, wv.z, a);
      a = FDOT2(sv.w, wv.w, a);
      ac[j] = a;
    }
  };
#pragma unroll
  for (int i = 0; i < 7; ++i) comp(0 + ks + 8*i, v1[i]);
#pragma unroll
  for (int i = 0; i < 7; ++i) comp(56 + ks + 8*i, v2[i]);
#pragma unroll
  for (int i = 0; i < 7; ++i) comp(112 + ks + 8*i, v3[i]);
  __syncthreads();
#pragma unroll
  for (int j = 0; j < 8; ++j) scrF[(ks*64 + b)*8 + j] = ac[j];
  __syncthreads();
  const int r = tid & 7, b2 = tid >> 3;
  float D = 0.f;
#pragma unroll
  for (int k = 0; k < 8; ++k) D += scrF[k*512 + tid];
  if (r < nr) P.GY[b2*128 + rlo + r] = D + bgl[r];
}

__device__ __forceinline__ void att_do(const Params& P, const unsigned* WAPH, unsigned* h1p,
    float* parts, float* abk, float* kapl, float* phi, float* winl,
    const float* batl, const int* csl, const int* cll, int b, int lb, int t) {
  const int tid = threadIdx.x;
  const int s1 = t & 3, sw = t & 1;
  if (tid < 224) h1p[tid] = ((const unsigned*)(P.H1H + (size_t)s1*HSLOT + (size_t)b*HROW))[tid];
  __syncthreads();
  if (tid < 240) {
    int j = tid >> 3, pp = tid & 7;
    const unsigned* wr = WAPH + j*200 + pp*25;
    const unsigned* hr = h1p + pp*25;
    float acc = 0.f;
#pragma unroll
    for (int m = 0; m < 25; ++m) acc = FDOT2(hr[m], wr[m], acc);
    parts[tid] = acc;
  }
  __syncthreads();
  if (tid < 30) {
    float s = batl[tid];
#pragma unroll
    for (int pp = 0; pp < 8; ++pp) s += parts[tid*8 + pp];
    abk[tid] = expf(s);
  }
  __syncthreads();
  if (tid < 10) kapl[lb*10 + tid] += abk[20 + tid];
  __syncthreads();
  if (tid < 50) {
    float s = 0.f;
    if (tid < cll[lb]) {
#pragma unroll
      for (int k = 0; k < 10; ++k) {
        float dk = kapl[lb*10 + k] - (float)tid;
        s += abk[k]*expf(-abk[10 + k]*dk*dk);
      }
    }
    phi[tid] = s;
  }
  __syncthreads();
  if (tid < 77) {
    float s = 0.f;
    for (int u = 0; u < 50; ++u) s += (csl[lb*50 + u] == tid) ? phi[u] : 0.f;
    winl[tid] = s;
  }
  __syncthreads();
  if (tid < 64) {
    int a0 = 2*tid, a1 = 2*tid + 1;
    h2v pk = { (_Float16)((a0 < 77) ? winl[a0] : 0.f),
               (_Float16)((a1 < 77) ? winl[a1] : 0.f) };
    *(unsigned*)(P.WINH + (size_t)sw*WSLOT + (size_t)b*WROW + a0) =
        __builtin_bit_cast(unsigned, pk);
  }
  __syncthreads();
}

__device__ __forceinline__ void yepi_do(const Params& P, float* rawl, float* smx, int b, int tt) {
  const int tid = threadIdx.x;
  __syncthreads();
  if (tid < 121) rawl[tid] = P.GY[b*128 + tid];
  __syncthreads();
  const float bia = P.bias[b];
  if (tid == 0) {
    float m = -1e30f;
    for (int j = 1; j <= 20; ++j) m = fmaxf(m, rawl[j]*(1.f + bia));
    float ss = 0.f;
    for (int j = 1; j <= 20; ++j) ss += expf(rawl[j]*(1.f + bia) - m);
    smx[0] = m; smx[1] = ss;
  }
  __syncthreads();
  float* yr = P.out + ((size_t)b*NT + tt)*121;
  if (tid == 0)           yr[120] = 1.f/(1.f + expf(-rawl[0]));
  else if (tid <= 20)     yr[tid - 1] = expf(rawl[tid]*(1.f + bia) - smx[0]) / smx[1];
  else if (tid <= 60)     yr[80 + tid - 21] = rawl[tid];
  else if (tid <= 100)    yr[20 + tid - 61] = expf(rawl[tid] - bia);
  else if (tid <= 120)    yr[60 + tid - 101] = tanhf(rawl[tid]);
  __syncthreads();
}

// =====================  persistent kernel: 156 WGs x 512 threads  =====================
__global__ __launch_bounds__(512, 1) void rnn_pers(Params P) {
  __shared__ __align__(16) char smem[69888];
  // mains carve:
  float* scr  = (float*)smem;                  // [8][64][21] f32 (43008 B)
  float* gsum = (float*)(smem + 43008);        // [64][21] f32 (5376 B)
  float* bcl  = (float*)(smem + 48384);        // 48 f32
  // aux carve (round-9 layout):
  _Float16* WH16 = (_Float16*)smem;            // gmm 168 chunks x 64 f16 (21504 B)
  const uint4* W4 = (const uint4*)smem;
  unsigned* WAPH = (unsigned*)(smem + 21504);  // Watt f16 pairs [30][200] (24000 B)
  float* scrF = (float*)(smem + 49536);        // [8][64][8] f32 (16384 B)
  float* M    = (float*)(smem + 65920);
  float* bgl  = M + 24;            // 8
  float* parts= M + 32;            // 240
  float* abk  = M + 272;           // 30
  float* kapl = M + 302;           // 20
  float* phi  = M + 322;           // 50
  float* winl = M + 372;           // 80
  float* batl = M + 452;           // 30
  float* rawl = M + 482;           // 121
  float* smx  = M + 603;           // 2
  unsigned* h1p = (unsigned*)(M + 605); // 224
  int*   csl  = (int*)(M + 829);   // 100
  int*   cll  = (int*)(M + 929);   // 2

  const int w = blockIdx.x, tid = threadIdx.x;
  const int ks = tid >> 6, l = tid & 63;
  int rlo = 0, nr = 0, blo = 0, bhi = 0;
  uint4 af1[3], af2[5], af3[6];

  if (w < NMAIN) {
    // ---- stage A-frags into registers (one-time) ----
    const int m = l & 15, dd = m >> 2, g = m & 3, gr = g*400 + 4*w + dd;
    const int kgo = (l >> 4)*8;
#pragma unroll
    for (int i = 0; i < 3; ++i) {
      const int kb = ks + 8*i;
      unsigned short u[8];
#pragma unroll
      for (int j = 0; j < 8; ++j) {
        float v = 0.f;
        if (kb < 19) {
          int kk = kb*32 + kgo + j;
          if (kk < 128)      { if (kk < 77) v = P.Wih1[(size_t)gr*80 + kk]; }
          else if (kk < 160) { int c = kk - 128; if (c < 3) v = P.Wih1[(size_t)gr*80 + 77 + c]; }
          else               { int c = kk - 160; if (c < 400) v = P.Whh1[(size_t)gr*400 + c]; }
        }
        u[j] = __builtin_bit_cast(unsigned short, (_Float16)v);
      }
      af1[i] = (uint4){(unsigned)u[0]|((unsigned)u[1]<<16), (unsigned)u[2]|((unsigned)u[3]<<16),
                       (unsigned)u[4]|((unsigned)u[5]<<16), (unsigned)u[6]|((unsigned)u[7]<<16)};
    }
#pragma unroll
    for (int i = 0; i < 5; ++i) {
      const int kb = ks + 8*i;
      unsigned short u[8];
#pragma unroll
      for (int j = 0; j < 8; ++j) {
        float v = 0.f;
        if (kb < 33) {
          int kk = kb*32 + kgo + j;
          if (kk < 32)       { if (kk < 3) v = P.Wih2[(size_t)gr*480 + kk]; }
          else if (kk < 480) { int c = kk - 32;  if (c < 400) v = P.Wih2[(size_t)gr*480 + 3 + c]; }
          else if (kk < 928) { int c = kk - 480; if (c < 400) v = P.Whh2[(size_t)gr*400 + c]; }
          else               { int c = kk - 928; if (c < 77)  v = P.Wih2[(size_t)gr*480 + 403 + c]; }
        }
        u[j] = __builtin_bit_cast(unsigned short, (_Float16)v);
      }
      af2[i] = (uint4){(unsigned)u[0]|((unsigned)u[1]<<16), (unsigned)u[2]|((unsigned)u[3]<<16),
                       (unsigned)u[4]|((unsigned)u[5]<<16), (unsigned)u[6]|((unsigned)u[7]<<16)};
    }
#pragma unroll
    for (int i = 0; i < 6; ++i) {
      const int kb = ks + 8*i;
      unsigned short u[8];
#pragma unroll
      for (int j = 0; j < 8; ++j) {
        float v = 0.f;
        if (kb < 47) {
          int kk = kb*32 + kgo + j;
          if (kk < 32)        { if (kk < 3) v = P.Wih3[(size_t)gr*880 + kk]; }
          else if (kk < 480)  { int c = kk - 32;   if (c < 400) v = P.Wih3[(size_t)gr*880 + 3 + c]; }
          else if (kk < 928)  { int c = kk - 480;  if (c < 400) v = P.Whh3[(size_t)gr*400 + c]; }
          else if (kk < 1376) { int c = kk - 928;  if (c < 400) v = P.Wih3[(size_t)gr*880 + 403 + c]; }
          else                { int c = kk - 1376; if (c < 77)  v = P.Wih3[(size_t)gr*880 + 803 + c]; }
        }
        u[j] = __builtin_bit_cast(unsigned short, (_Float16)v);
      }
      af3[i] = (uint4){(unsigned)u[0]|((unsigned)u[1]<<16), (unsigned)u[2]|((unsigned)u[3]<<16),
                       (unsigned)u[4]|((unsigned)u[5]<<16), (unsigned)u[6]|((unsigned)u[7]<<16)};
    }
    if (tid < 48) {
      int L = tid >> 4, mm = tid & 15, ddb = mm >> 2, gb = mm & 3;
      bcl[tid] = P.BC[L*1600 + gb*400 + 4*w + ddb];
    }
  } else {
    const int q = w - NMAIN;
    rlo = (121*q)/NAUX;
    nr  = (121*(q+1))/NAUX - rlo;
    blo = (64*q)/NAUX;
    bhi = (64*(q+1))/NAUX;
    for (int j = 0; j < 8; ++j) {
      for (int k = tid; k < 448; k += 512) {
        float a = (j < nr && k < 400) ? P.Wgmm[(size_t)(rlo + j)*1200 + k] : 0.f;
        float bv = (j < nr && k < 400) ? P.Wgmm[(size_t)(rlo + j)*1200 + 400 + k] : 0.f;
        float cv = (j < nr && k < 400) ? P.Wgmm[(size_t)(rlo + j)*1200 + 800 + k] : 0.f;
        WH16[(0 + (k>>3))*64 + j*8 + (k&7)]   = (_Float16)a;
        WH16[(56 + (k>>3))*64 + j*8 + (k&7)]  = (_Float16)bv;
        WH16[(112 + (k>>3))*64 + j*8 + (k&7)] = (_Float16)cv;
      }
    }
    if (tid < 8) bgl[tid] = (tid < nr) ? P.bgmm[rlo + tid] : 0.f;
    for (int i = tid; i < 6000; i += 512) {
      int j = i / 200, pr = i % 200;
      h2v pk = { (_Float16)P.Watt[j*400 + 2*pr], (_Float16)P.Watt[j*400 + 2*pr + 1] };
      WAPH[i] = __builtin_bit_cast(unsigned, pk);
    }
    if (tid < 30) batl[tid] = P.batt[tid];
    for (int lb = 0; lb < bhi - blo; ++lb) {
      if (tid < 50) csl[lb*50 + tid] = P.cs[(blo + lb)*50 + tid];
      if (tid == 0) cll[lb] = P.cl[blo + lb];
    }
    if (tid < 20) kapl[tid] = 0.f;
  }
  __syncthreads();

  int ph = 0;
  float c1 = 0.f, c2 = 0.f, c3 = 0.f;
  for (int t = 0; t <= NT + 1; ++t) {
    const bool doL1 = (t < NT), doL2 = (t >= 1 && t <= NT), doAux = (t >= 2);
    // ======== Phase A: L1(t) + L2(t-1) on mains || GMM(t-2) on aux ========
    if (w < NMAIN) {
      if (doL1) mfma_layer<0, 19, 3>(P, af1, scr, gsum, bcl, w, t,     c1,
                                     P.H1H + (size_t)(t & 3)*HSLOT);
      if (doL2) mfma_layer<1, 33, 5>(P, af2, scr, gsum, bcl, w, t - 1, c2,
                                     P.H2H + (size_t)((t - 1) & 1)*HSLOT);
    } else {
      if (doAux) gmm_do(P, W4, scrF, bgl, rlo, nr, t - 2);
    }
    tbar(P.CNT, w, ph);
    // ======== Phase B: L3(t-1) on mains || att(t) + yepi(t-2) on aux ========
    if (w < NMAIN) {
      if (doL2) mfma_layer<2, 47, 6>(P, af3, scr, gsum, bcl, w, t - 1, c3,
                                     P.H3H + (size_t)((t - 1) & 1)*HSLOT);
    } else {
      if (doL1)
        for (int lb = 0; lb < bhi - blo; ++lb)
          att_do(P, WAPH, h1p, parts, abk, kapl, phi, winl, batl, csl, cll, blo + lb, lb, t);
      if (doAux)
        for (int lb = 0; lb < bhi - blo; ++lb)
          yepi_do(P, rawl, smx, blo + lb, t - 2);
    }
    tbar(P.CNT, w, ph);
  }
}

extern "C" void kernel_launch(void* const* d_in, const int* in_sizes, int n_in,
                              void* d_out, int out_size, void* d_ws, size_t ws_size,
                              hipStream_t stream) {
  (void)in_sizes; (void)n_in; (void)out_size; (void)ws_size;
  Params P;
  P.x    = (const float*)d_in[0];
  P.cs   = (const int*)d_in[1];
  P.cl   = (const int*)d_in[2];
  P.bias = (const float*)d_in[3];
  P.Wih1 = (const float*)d_in[4];  P.Whh1 = (const float*)d_in[5];
  P.bih1 = (const float*)d_in[6];  P.bhh1 = (const float*)d_in[7];
  P.Wih2 = (const float*)d_in[8];  P.Whh2 = (const float*)d_in[9];
  P.bih2 = (const float*)d_in[10]; P.bhh2 = (const float*)d_in[11];
  P.Wih3 = (const float*)d_in[12]; P.Whh3 = (const float*)d_in[13];
  P.bih3 = (const float*)d_in[14]; P.bhh3 = (const float*)d_in[15];
  P.Watt = (const float*)d_in[16]; P.batt = (const float*)d_in[17];
  P.Wgmm = (const float*)d_in[18]; P.bgmm = (const float*)d_in[19];
  char* ws = (char*)d_ws;
  P.XTH  = (_Float16*)(ws + OFF_XTH);
  P.H1H  = (_Float16*)(ws + OFF_H1H);
  P.H2H  = (_Float16*)(ws + OFF_H2H);
  P.H3H  = (_Float16*)(ws + OFF_H3H);
  P.WINH = (_Float16*)(ws + OFF_WINH);
  P.BC   = (float*)(ws + OFF_BC);
  P.GY   = (float*)(ws + OFF_GY);
  P.CNT  = (int*)(ws + OFF_CNT);
  P.out  = (float*)d_out;

  hipLaunchKernelGGL(prep_k, dim3(1024), dim3(256), 0, stream, P);
  hipLaunchKernelGGL(rnn_pers, dim3(NWG), dim3(512), 0, stream, P);
}

// Round 11
// 18229.245 us; speedup vs baseline: 14.2002x; 1.0607x over previous
//
#include <hip/hip_runtime.h>
#include <stdint.h>

#define NT 600
#define NMAIN 100
#define NWG 156
#define NAUX (NWG - NMAIN)

// ---- ws layout (bytes) ----
#define OFF_XTH  0          // [600][64][32]  f16  2457600
#define OFF_H1H  2457600    // [4][64][448]   f16  229376
#define OFF_H2H  2686976    // [2][64][448]   f16  114688
#define OFF_H3H  2801664    // [2][64][448]   f16  114688
#define OFF_WINH 2916352    // [2][64][128]   f16  32768
#define OFF_BC   2949120    // [3][1600]      f32  19200
#define OFF_GY   2968320    // [2][64][128]   f32  65536
#define OFF_CNT  3033856    // [12*32]        i32  2048

#define HROW 448
#define HSLOT 28672   // 64*448
#define WROW 128
#define WSLOT 8192    // 64*128
#define XROW 32
#define GYSLOT 8192   // 64*128 f32

typedef _Float16 h2v __attribute__((ext_vector_type(2)));
typedef _Float16 f16x8 __attribute__((ext_vector_type(8)));
typedef float f32x4 __attribute__((ext_vector_type(4)));

struct Params {
  const float* x; const int* cs; const int* cl; const float* bias;
  const float *Wih1,*Whh1,*bih1,*bhh1,*Wih2,*Whh2,*bih2,*bhh2,*Wih3,*Whh3,*bih3,*bhh3;
  const float *Watt,*batt,*Wgmm,*bgmm;
  _Float16 *XTH,*H1H,*H2H,*H3H,*WINH;
  float *BC,*GY;
  int *CNT;
  float* out;
};

__device__ __forceinline__ float sigm(float x) { return 1.f / (1.f + expf(-x)); }

__device__ __forceinline__ float FDOT2(unsigned a, unsigned b, float c) {
#if __has_builtin(__builtin_amdgcn_fdot2)
  return __builtin_amdgcn_fdot2(__builtin_bit_cast(h2v, a), __builtin_bit_cast(h2v, b), c, false);
#else
  h2v x = __builtin_bit_cast(h2v, a), y = __builtin_bit_cast(h2v, b);
  return c + (float)x[0]*(float)y[0] + (float)x[1]*(float)y[1];
#endif
}

// 12-sub-counter barrier over 156 WGs (13 per sub-counter)
__device__ __forceinline__ void tbar(int* C, int w, int& ph) {
  __syncthreads();
  if (threadIdx.x == 0)
    __hip_atomic_fetch_add(&C[(w % 12)*32], 1, __ATOMIC_RELEASE, __HIP_MEMORY_SCOPE_AGENT);
  ++ph;
  const int tgt = 13*ph;
  if (threadIdx.x < 12) {
    while (__hip_atomic_load(&C[threadIdx.x*32], __ATOMIC_RELAXED, __HIP_MEMORY_SCOPE_AGENT) < tgt)
      __builtin_amdgcn_s_sleep(1);
    (void)__hip_atomic_load(&C[threadIdx.x*32], __ATOMIC_ACQUIRE, __HIP_MEMORY_SCOPE_AGENT);
  }
  __syncthreads();
}

// =====================  prep  =====================
__global__ void prep_k(Params P) {
  const long long NX  = 600LL*64*32;
  const long long NH1 = 4LL*64*448;
  const long long NH2 = 2LL*64*448;
  const long long NWH = 2LL*64*128;
  const long long NBc = 4800;
  const long long NCt = 512;
  const long long TOT = NX + NH1 + 2*NH2 + NWH + NBc + NCt;
  const long long stride = (long long)gridDim.x * blockDim.x;
  for (long long idx = (long long)blockIdx.x*blockDim.x + threadIdx.x; idx < TOT; idx += stride) {
    long long i = idx;
    if (i < NX) {
      int t = (int)(i >> 11);
      int rem = (int)(i & 2047);
      int b = rem >> 5, k = rem & 31;
      float v = (k < 3) ? P.x[((size_t)b*NT + t)*3 + k] : 0.f;
      P.XTH[i] = (_Float16)v;
      continue;
    }
    i -= NX;
    if (i < NH1) { P.H1H[i] = (_Float16)0.f; continue; } i -= NH1;
    if (i < NH2) { P.H2H[i] = (_Float16)0.f; continue; } i -= NH2;
    if (i < NH2) { P.H3H[i] = (_Float16)0.f; continue; } i -= NH2;
    if (i < NWH) { P.WINH[i] = (_Float16)0.f; continue; } i -= NWH;
    if (i < NBc) {
      int l = (int)(i / 1600), r = (int)(i % 1600);
      const float* bi = (l==0)?P.bih1:(l==1)?P.bih2:P.bih3;
      const float* bh = (l==0)?P.bhh1:(l==1)?P.bhh2:P.bhh3;
      P.BC[i] = bi[r] + bh[r];
      continue;
    }
    i -= NBc;
    P.CNT[i] = 0;
  }
}

// =====================  MFMA LSTM layer (verified round-10)  =====================
template<int L, int NBLK, int MAXI>
__device__ __forceinline__ void mfma_layer(const Params& P, const uint4* af,
    float* scr, float* gsum, const float* bcl, int w, int tt, float& cref, _Float16* Hout) {
  const int tid = threadIdx.x, ks = tid >> 6, l = tid & 63;
  uint4 bf[MAXI][4];
#pragma unroll
  for (int i = 0; i < MAXI; ++i) {
    const int kb = ks + 8*i;
    if (kb < NBLK) {
      const _Float16* bp; int k0, st;
      if constexpr (L == 0) {
        if (kb < 4)       { bp = P.WINH + (size_t)((tt+1)&1)*WSLOT; st = WROW; k0 = kb*32; }
        else if (kb == 4) { bp = P.XTH + (size_t)tt*2048;           st = XROW; k0 = 0; }
        else              { bp = P.H1H + (size_t)((tt+3)&3)*HSLOT;  st = HROW; k0 = (kb-5)*32; }
      } else if constexpr (L == 1) {
        if (kb == 0)      { bp = P.XTH + (size_t)tt*2048;           st = XROW; k0 = 0; }
        else if (kb < 15) { bp = P.H1H + (size_t)(tt&3)*HSLOT;      st = HROW; k0 = (kb-1)*32; }
        else if (kb < 29) { bp = P.H2H + (size_t)((tt+1)&1)*HSLOT;  st = HROW; k0 = (kb-15)*32; }
        else              { bp = P.WINH + (size_t)(tt&1)*WSLOT;     st = WROW; k0 = (kb-29)*32; }
      } else {
        if (kb == 0)      { bp = P.XTH + (size_t)tt*2048;           st = XROW; k0 = 0; }
        else if (kb < 15) { bp = P.H1H + (size_t)(tt&3)*HSLOT;      st = HROW; k0 = (kb-1)*32; }
        else if (kb < 29) { bp = P.H3H + (size_t)((tt+1)&1)*HSLOT;  st = HROW; k0 = (kb-15)*32; }
        else if (kb < 43) { bp = P.H2H + (size_t)(tt&1)*HSLOT;      st = HROW; k0 = (kb-29)*32; }
        else              { bp = P.WINH + (size_t)(tt&1)*WSLOT;     st = WROW; k0 = (kb-43)*32; }
      }
      const _Float16* base = bp + (size_t)(l & 15)*st + k0 + ((l >> 4)*8);
#pragma unroll
      for (int ct = 0; ct < 4; ++ct)
        bf[i][ct] = *(const uint4*)(base + (size_t)ct*16*st);
    }
  }
  f32x4 acc[4] = {{0.f,0.f,0.f,0.f},{0.f,0.f,0.f,0.f},{0.f,0.f,0.f,0.f},{0.f,0.f,0.f,0.f}};
#pragma unroll
  for (int i = 0; i < MAXI; ++i) {
    const int kb = ks + 8*i;
    if (kb < NBLK) {
#pragma unroll
      for (int ct = 0; ct < 4; ++ct)
        acc[ct] = __builtin_amdgcn_mfma_f32_16x16x32_f16(
            __builtin_bit_cast(f16x8, af[i]), __builtin_bit_cast(f16x8, bf[i][ct]),
            acc[ct], 0, 0, 0);
    }
  }
  __syncthreads();
#pragma unroll
  for (int ct = 0; ct < 4; ++ct)
    *(f32x4*)&scr[((size_t)(ks*64 + ct*16 + (l & 15)))*21 + (l >> 4)*4] = acc[ct];
  __syncthreads();
#pragma unroll
  for (int p = 0; p < 2; ++p) {
    const int idx = tid + p*512, m = idx >> 6, b = idx & 63;
    float s = 0.f;
#pragma unroll
    for (int k = 0; k < 8; ++k) s += scr[(size_t)(k*64 + b)*21 + m];
    gsum[b*21 + m] = s + bcl[L*16 + m];
  }
  __syncthreads();
  if (tid < 256) {
    const int dd = tid >> 6, b = tid & 63;
    const float* gp = gsum + b*21 + dd*4;
    float c = sigm(gp[1])*cref + sigm(gp[0])*tanhf(gp[2]);
    cref = c;
    float h = sigm(gp[3])*tanhf(c);
    Hout[(size_t)b*HROW + 4*w + dd] = (_Float16)h;
  }
}

// =====================  GMM via MFMA: aux WG q<8 owns rows q*16..q*16+15  =====================
__device__ __forceinline__ void gmm_mfma(const Params& P, const uint4* afg,
    float* scr, const float* bgl, int rlo, int tt) {
  const int tid = threadIdx.x, ks = tid >> 6, l = tid & 63;
  const _Float16* h1 = P.H1H + (size_t)(tt & 3)*HSLOT;
  const _Float16* h2 = P.H2H + (size_t)(tt & 1)*HSLOT;
  const _Float16* h3 = P.H3H + (size_t)(tt & 1)*HSLOT;
  uint4 bf[6][4];
#pragma unroll
  for (int i = 0; i < 6; ++i) {
    const int kb = ks + 8*i;
    if (kb < 42) {
      const _Float16* bp; int k0;
      if (kb < 14)      { bp = h1; k0 = kb*32; }
      else if (kb < 28) { bp = h2; k0 = (kb-14)*32; }
      else              { bp = h3; k0 = (kb-28)*32; }
      const _Float16* base = bp + (size_t)(l & 15)*HROW + k0 + ((l >> 4)*8);
#pragma unroll
      for (int ct = 0; ct < 4; ++ct)
        bf[i][ct] = *(const uint4*)(base + (size_t)ct*16*HROW);
    }
  }
  f32x4 acc[4] = {{0.f,0.f,0.f,0.f},{0.f,0.f,0.f,0.f},{0.f,0.f,0.f,0.f},{0.f,0.f,0.f,0.f}};
#pragma unroll
  for (int i = 0; i < 6; ++i) {
    const int kb = ks + 8*i;
    if (kb < 42) {
#pragma unroll
      for (int ct = 0; ct < 4; ++ct)
        acc[ct] = __builtin_amdgcn_mfma_f32_16x16x32_f16(
            __builtin_bit_cast(f16x8, afg[i]), __builtin_bit_cast(f16x8, bf[i][ct]),
            acc[ct], 0, 0, 0);
    }
  }
  __syncthreads();
#pragma unroll
  for (int ct = 0; ct < 4; ++ct)
    *(f32x4*)&scr[((size_t)(ks*64 + ct*16 + (l & 15)))*17 + (l >> 4)*4] = acc[ct];
  __syncthreads();
  float* gy = P.GY + (size_t)(tt & 1)*GYSLOT;
#pragma unroll
  for (int p = 0; p < 2; ++p) {
    const int idx = tid + p*512, m = idx >> 6, b = idx & 63;
    float s = 0.f;
#pragma unroll
    for (int k = 0; k < 8; ++k) s += scr[(size_t)(k*64 + b)*17 + m];
    const int r = rlo + m;
    if (r < 121) gy[b*128 + r] = s + bgl[m];
  }
  __syncthreads();
}

// attention window (verified round-10)
__device__ __forceinline__ void att_do(const Params& P, const unsigned* WAPH, unsigned* h1p,
    float* parts, float* abk, float* kapl, float* phi, float* winl,
    const float* batl, const int* csl, const int* cll, int b, int lb, int t) {
  const int tid = threadIdx.x;
  const int s1 = t & 3, sw = t & 1;
  if (tid < 224) h1p[tid] = ((const unsigned*)(P.H1H + (size_t)s1*HSLOT + (size_t)b*HROW))[tid];
  __syncthreads();
  if (tid < 240) {
    int j = tid >> 3, pp = tid & 7;
    const unsigned* wr = WAPH + j*200 + pp*25;
    const unsigned* hr = h1p + pp*25;
    float acc = 0.f;
#pragma unroll
    for (int m = 0; m < 25; ++m) acc = FDOT2(hr[m], wr[m], acc);
    parts[tid] = acc;
  }
  __syncthreads();
  if (tid < 30) {
    float s = batl[tid];
#pragma unroll
    for (int pp = 0; pp < 8; ++pp) s += parts[tid*8 + pp];
    abk[tid] = expf(s);
  }
  __syncthreads();
  if (tid < 10) kapl[lb*10 + tid] += abk[20 + tid];
  __syncthreads();
  if (tid < 50) {
    float s = 0.f;
    if (tid < cll[lb]) {
#pragma unroll
      for (int k = 0; k < 10; ++k) {
        float dk = kapl[lb*10 + k] - (float)tid;
        s += abk[k]*expf(-abk[10 + k]*dk*dk);
      }
    }
    phi[tid] = s;
  }
  __syncthreads();
  if (tid < 77) {
    float s = 0.f;
    for (int u = 0; u < 50; ++u) s += (csl[lb*50 + u] == tid) ? phi[u] : 0.f;
    winl[tid] = s;
  }
  __syncthreads();
  if (tid < 64) {
    int a0 = 2*tid, a1 = 2*tid + 1;
    h2v pk = { (_Float16)((a0 < 77) ? winl[a0] : 0.f),
               (_Float16)((a1 < 77) ? winl[a1] : 0.f) };
    *(unsigned*)(P.WINH + (size_t)sw*WSLOT + (size_t)b*WROW + a0) =
        __builtin_bit_cast(unsigned, pk);
  }
  __syncthreads();
}

// y epilogue (verified round-10; gy = GY slot base)
__device__ __forceinline__ void yepi_do(const Params& P, const float* gy,
                                        float* rawl, float* smx, int b, int tt) {
  const int tid = threadIdx.x;
  __syncthreads();
  if (tid < 121) rawl[tid] = gy[b*128 + tid];
  __syncthreads();
  const float bia = P.bias[b];
  if (tid == 0) {
    float m = -1e30f;
    for (int j = 1; j <= 20; ++j) m = fmaxf(m, rawl[j]*(1.f + bia));
    float ss = 0.f;
    for (int j = 1; j <= 20; ++j) ss += expf(rawl[j]*(1.f + bia) - m);
    smx[0] = m; smx[1] = ss;
  }
  __syncthreads();
  float* yr = P.out + ((size_t)b*NT + tt)*121;
  if (tid == 0)           yr[120] = 1.f/(1.f + expf(-rawl[0]));
  else if (tid <= 20)     yr[tid - 1] = expf(rawl[tid]*(1.f + bia) - smx[0]) / smx[1];
  else if (tid <= 60)     yr[80 + tid - 21] = rawl[tid];
  else if (tid <= 100)    yr[20 + tid - 61] = expf(rawl[tid] - bia);
  else if (tid <= 120)    yr[60 + tid - 101] = tanhf(rawl[tid]);
  __syncthreads();
}

// =====================  persistent kernel: 156 WGs x 512 threads  =====================
__global__ __launch_bounds__(512, 1) void rnn_pers(Params P) {
  __shared__ __align__(16) char smem[69888];
  // mains carve:
  float* scr  = (float*)smem;                  // [8][64][21] f32 (43008 B)
  float* gsum = (float*)(smem + 43008);        // [64][21] f32 (5376 B)
  float* bcl  = (float*)(smem + 48384);        // 48 f32
  // aux carve:
  float* scrg = (float*)smem;                  // [8][64][17] f32 (34816 B)  q<8 only
  unsigned* WAPH = (unsigned*)(smem + 39168);  // Watt f16 pairs [30][200] (24000 B)
  float* M    = (float*)(smem + 63168);
  float* bgl  = M;                 // 16
  float* parts= M + 16;            // 240
  float* abk  = M + 256;           // 30
  float* kapl = M + 286;           // 20
  float* phi  = M + 306;           // 50
  float* winl = M + 356;           // 80
  float* batl = M + 436;           // 30
  float* rawl = M + 466;           // 121
  float* smx  = M + 587;           // 2
  unsigned* h1p = (unsigned*)(M + 589); // 224
  int*   csl  = (int*)(M + 813);   // 100
  int*   cll  = (int*)(M + 913);   // 2

  const int w = blockIdx.x, tid = threadIdx.x;
  const int ks = tid >> 6, l = tid & 63;
  int blo = 0, bhi = 0, ylo = 0, yhi = 0;
  uint4 af1[3], af2[5], af3[6], afg[6];

  if (w < NMAIN) {
    // ---- stage LSTM A-frags into registers (verified round-10) ----
    const int m = l & 15, dd = m >> 2, g = m & 3, gr = g*400 + 4*w + dd;
    const int kgo = (l >> 4)*8;
#pragma unroll
    for (int i = 0; i < 3; ++i) {
      const int kb = ks + 8*i;
      unsigned short u[8];
#pragma unroll
      for (int j = 0; j < 8; ++j) {
        float v = 0.f;
        if (kb < 19) {
          int kk = kb*32 + kgo + j;
          if (kk < 128)      { if (kk < 77) v = P.Wih1[(size_t)gr*80 + kk]; }
          else if (kk < 160) { int c = kk - 128; if (c < 3) v = P.Wih1[(size_t)gr*80 + 77 + c]; }
          else               { int c = kk - 160; if (c < 400) v = P.Whh1[(size_t)gr*400 + c]; }
        }
        u[j] = __builtin_bit_cast(unsigned short, (_Float16)v);
      }
      af1[i] = (uint4){(unsigned)u[0]|((unsigned)u[1]<<16), (unsigned)u[2]|((unsigned)u[3]<<16),
                       (unsigned)u[4]|((unsigned)u[5]<<16), (unsigned)u[6]|((unsigned)u[7]<<16)};
    }
#pragma unroll
    for (int i = 0; i < 5; ++i) {
      const int kb = ks + 8*i;
      unsigned short u[8];
#pragma unroll
      for (int j = 0; j < 8; ++j) {
        float v = 0.f;
        if (kb < 33) {
          int kk = kb*32 + kgo + j;
          if (kk < 32)       { if (kk < 3) v = P.Wih2[(size_t)gr*480 + kk]; }
          else if (kk < 480) { int c = kk - 32;  if (c < 400) v = P.Wih2[(size_t)gr*480 + 3 + c]; }
          else if (kk < 928) { int c = kk - 480; if (c < 400) v = P.Whh2[(size_t)gr*400 + c]; }
          else               { int c = kk - 928; if (c < 77)  v = P.Wih2[(size_t)gr*480 + 403 + c]; }
        }
        u[j] = __builtin_bit_cast(unsigned short, (_Float16)v);
      }
      af2[i] = (uint4){(unsigned)u[0]|((unsigned)u[1]<<16), (unsigned)u[2]|((unsigned)u[3]<<16),
                       (unsigned)u[4]|((unsigned)u[5]<<16), (unsigned)u[6]|((unsigned)u[7]<<16)};
    }
#pragma unroll
    for (int i = 0; i < 6; ++i) {
      const int kb = ks + 8*i;
      unsigned short u[8];
#pragma unroll
      for (int j = 0; j < 8; ++j) {
        float v = 0.f;
        if (kb < 47) {
          int kk = kb*32 + kgo + j;
          if (kk < 32)        { if (kk < 3) v = P.Wih3[(size_t)gr*880 + kk]; }
          else if (kk < 480)  { int c = kk - 32;   if (c < 400) v = P.Wih3[(size_t)gr*880 + 3 + c]; }
          else if (kk < 928)  { int c = kk - 480;  if (c < 400) v = P.Whh3[(size_t)gr*400 + c]; }
          else if (kk < 1376) { int c = kk - 928;  if (c < 400) v = P.Wih3[(size_t)gr*880 + 403 + c]; }
          else                { int c = kk - 1376; if (c < 77)  v = P.Wih3[(size_t)gr*880 + 803 + c]; }
        }
        u[j] = __builtin_bit_cast(unsigned short, (_Float16)v);
      }
      af3[i] = (uint4){(unsigned)u[0]|((unsigned)u[1]<<16), (unsigned)u[2]|((unsigned)u[3]<<16),
                       (unsigned)u[4]|((unsigned)u[5]<<16), (unsigned)u[6]|((unsigned)u[7]<<16)};
    }
    if (tid < 48) {
      int L = tid >> 4, mm = tid & 15, ddb = mm >> 2, gb = mm & 3;
      bcl[tid] = P.BC[L*1600 + gb*400 + 4*w + ddb];
    }
  } else {
    const int q = w - NMAIN;
    blo = (64*q)/NAUX;  bhi = (64*(q+1))/NAUX;
    if (q >= 8) { ylo = (64*(q-8))/48; yhi = (64*(q-7))/48; }
    if (q < 8) {
      // stage GMM A-frags: rows q*16+m, K = h1[0,448)|h2[448,896)|h3[896,1344)
      const int m = l & 15, gr = q*16 + m;
      const int kgo = (l >> 4)*8;
#pragma unroll
      for (int i = 0; i < 6; ++i) {
        const int kb = ks + 8*i;
        unsigned short u[8];
#pragma unroll
        for (int j = 0; j < 8; ++j) {
          float v = 0.f;
          if (kb < 42 && gr < 121) {
            int kk = kb*32 + kgo + j;
            if (kk < 448)      { if (kk < 400) v = P.Wgmm[(size_t)gr*1200 + kk]; }
            else if (kk < 896) { int c = kk - 448; if (c < 400) v = P.Wgmm[(size_t)gr*1200 + 400 + c]; }
            else               { int c = kk - 896; if (c < 400) v = P.Wgmm[(size_t)gr*1200 + 800 + c]; }
          }
          u[j] = __builtin_bit_cast(unsigned short, (_Float16)v);
        }
        afg[i] = (uint4){(unsigned)u[0]|((unsigned)u[1]<<16), (unsigned)u[2]|((unsigned)u[3]<<16),
                         (unsigned)u[4]|((unsigned)u[5]<<16), (unsigned)u[6]|((unsigned)u[7]<<16)};
      }
      if (tid < 16) bgl[tid] = (q*16 + tid < 121) ? P.bgmm[q*16 + tid] : 0.f;
    }
    for (int i = tid; i < 6000; i += 512) {
      int j = i / 200, pr = i % 200;
      h2v pk = { (_Float16)P.Watt[j*400 + 2*pr], (_Float16)P.Watt[j*400 + 2*pr + 1] };
      WAPH[i] = __builtin_bit_cast(unsigned, pk);
    }
    if (tid < 30) batl[tid] = P.batt[tid];
    for (int lb = 0; lb < bhi - blo; ++lb) {
      if (tid < 50) csl[lb*50 + tid] = P.cs[(blo + lb)*50 + tid];
      if (tid == 0) cll[lb] = P.cl[blo + lb];
    }
    if (tid < 20) kapl[tid] = 0.f;
  }
  __syncthreads();

  int ph = 0;
  float c1 = 0.f, c2 = 0.f, c3 = 0.f;
  for (int t = 0; t <= NT + 2; ++t) {
    const bool doL1 = (t < NT), doL23 = (t >= 1 && t <= NT);
    const bool doG = (t >= 2 && t <= NT + 1), doY = (t >= 3);
    // ======== Phase A: L1(t)+L2(t-1) mains || GMM(t-2) aux<8 | yepi(t-3) aux>=8 ========
    if (w < NMAIN) {
      if (doL1)  mfma_layer<0, 19, 3>(P, af1, scr, gsum, bcl, w, t,     c1,
                                      P.H1H + (size_t)(t & 3)*HSLOT);
      if (doL23) mfma_layer<1, 33, 5>(P, af2, scr, gsum, bcl, w, t - 1, c2,
                                      P.H2H + (size_t)((t - 1) & 1)*HSLOT);
    } else {
      const int q = w - NMAIN;
      if (q < 8) {
        if (doG) gmm_mfma(P, afg, scrg, bgl, q*16, t - 2);
      } else if (doY) {
        const float* gy = P.GY + (size_t)((t - 3) & 1)*GYSLOT;
        for (int yb = ylo; yb < yhi; ++yb)
          yepi_do(P, gy, rawl, smx, yb, t - 3);
      }
    }
    tbar(P.CNT, w, ph);
    // ======== Phase B: L3(t-1) mains || att(t) aux ========
    if (w < NMAIN) {
      if (doL23) mfma_layer<2, 47, 6>(P, af3, scr, gsum, bcl, w, t - 1, c3,
                                      P.H3H + (size_t)((t - 1) & 1)*HSLOT);
    } else {
      if (doL1)
        for (int lb = 0; lb < bhi - blo; ++lb)
          att_do(P, WAPH, h1p, parts, abk, kapl, phi, winl, batl, csl, cll, blo + lb, lb, t);
    }
    tbar(P.CNT, w, ph);
  }
}

extern "C" void kernel_launch(void* const* d_in, const int* in_sizes, int n_in,
                              void* d_out, int out_size, void* d_ws, size_t ws_size,
                              hipStream_t stream) {
  (void)in_sizes; (void)n_in; (void)out_size; (void)ws_size;
  Params P;
  P.x    = (const float*)d_in[0];
  P.cs   = (const int*)d_in[1];
  P.cl   = (const int*)d_in[2];
  P.bias = (const float*)d_in[3];
  P.Wih1 = (const float*)d_in[4];  P.Whh1 = (const float*)d_in[5];
  P.bih1 = (const float*)d_in[6];  P.bhh1 = (const float*)d_in[7];
  P.Wih2 = (const float*)d_in[8];  P.Whh2 = (const float*)d_in[9];
  P.bih2 = (const float*)d_in[10]; P.bhh2 = (const float*)d_in[11];
  P.Wih3 = (const float*)d_in[12]; P.Whh3 = (const float*)d_in[13];
  P.bih3 = (const float*)d_in[14]; P.bhh3 = (const float*)d_in[15];
  P.Watt = (const float*)d_in[16]; P.batt = (const float*)d_in[17];
  P.Wgmm = (const float*)d_in[18]; P.bgmm = (const float*)d_in[19];
  char* ws = (char*)d_ws;
  P.XTH  = (_Float16*)(ws + OFF_XTH);
  P.H1H  = (_Float16*)(ws + OFF_H1H);
  P.H2H  = (_Float16*)(ws + OFF_H2H);
  P.H3H  = (_Float16*)(ws + OFF_H3H);
  P.WINH = (_Float16*)(ws + OFF_WINH);
  P.BC   = (float*)(ws + OFF_BC);
  P.GY   = (float*)(ws + OFF_GY);
  P.CNT  = (int*)(ws + OFF_CNT);
  P.out  = (float*)d_out;

  hipLaunchKernelGGL(prep_k, dim3(1024), dim3(256), 0, stream, P);
  hipLaunchKernelGGL(rnn_pers, dim3(NWG), dim3(512), 0, stream, P);
}